// Round 5
// baseline (4555.572 us; speedup 1.0000x reference)
//
#include <hip/hip_runtime.h>
#include <math.h>
#include <stdint.h>

// EMACE forward, f32.
// R5 structure: edge-parallel GEMM for the radial MLP.
//  1) node_init, edge CSR build (count/scan/fill)
//  2) per layer:
//     a) mlp123_k: L1+L2+L3 for all active edges, 8x8 register-blocked
//        f32 GEMM on 256-edge LDS tiles -> act3[e][64]
//     b) node_gather_k: fused L4 (shfl-broadcast x, LDS W4T reused across
//        4-edge batches) + Y message accumulation + node update + readout
//  3) write_out

#define PI_F 3.14159265358979323846f
#define ECAP 100000  // active-edge capacity (expected ~46k, hard stat bound)

__device__ __forceinline__ float silu_f(float x) { return x / (1.f + __expf(-x)); }

#define LDSFENCE() asm volatile("s_waitcnt lgkmcnt(0)" ::: "memory")

// ---------------------------------------------------------------- node init
__global__ void node_init_k(const float* __restrict__ attrs,
                            const float* __restrict__ ae,
                            const float* __restrict__ Wemb,
                            const int* __restrict__ batch,
                            float* __restrict__ h0, int* __restrict__ spec,
                            float* __restrict__ energy, int N, int NE) {
  int n = (int)((blockIdx.x * blockDim.x + threadIdx.x) >> 6);
  int lane = threadIdx.x & 63;
  if (n >= N) return;
  const float* a = attrs + (size_t)n * NE;
  int sp = 0;
  for (int e = 0; e < NE; ++e)
    if (a[e] > 0.5f) sp = e;
  h0[(size_t)n * 64 + lane] = Wemb[sp * 64 + lane];
  if (lane == 0) spec[n] = sp;
  if (lane < 3) atomicAdd(&energy[batch[n] * 3 + lane], ae[sp]);
}

// ---------------------------------------------------------------- edge pass 1
__global__ void edge_count_k(const float* __restrict__ pos,
                             const float* __restrict__ shifts,
                             const int* __restrict__ ei,
                             int* __restrict__ deg, int E) {
  int e = blockIdx.x * blockDim.x + threadIdx.x;
  if (e >= E) return;
  int s = ei[e], r = ei[E + e];
  float dx = pos[r * 3 + 0] - pos[s * 3 + 0] + shifts[e * 3 + 0];
  float dy = pos[r * 3 + 1] - pos[s * 3 + 1] + shifts[e * 3 + 1];
  float dz = pos[r * 3 + 2] - pos[s * 3 + 2] + shifts[e * 3 + 2];
  float d2 = dx * dx + dy * dy + dz * dz;
  if (d2 < 25.0f) atomicAdd(&deg[r], 1);
}

// ---------------------------------------------------------------- scan
__global__ void scan_deg_k(const int* __restrict__ deg, int* __restrict__ off,
                           int N) {
  __shared__ int sdat[1024];
  int tid = threadIdx.x;
  int chunk = (N + 1023) / 1024;
  int s0 = tid * chunk, s1 = min(s0 + chunk, N);
  int s = 0;
  for (int i = s0; i < s1; ++i) s += deg[i];
  sdat[tid] = s;
  __syncthreads();
  for (int d = 1; d < 1024; d <<= 1) {
    int v = (tid >= d) ? sdat[tid - d] : 0;
    __syncthreads();
    sdat[tid] += v;
    __syncthreads();
  }
  int run = sdat[tid] - s;  // exclusive prefix
  for (int i = s0; i < s1; ++i) {
    off[i] = run;
    run += deg[i];
  }
  if (tid == 1023) off[N] = sdat[1023];
}

// ---------------------------------------------------------------- edge pass 2
__global__ void edge_fill_k(const float* __restrict__ pos,
                            const float* __restrict__ shifts,
                            const int* __restrict__ ei,
                            const int* __restrict__ off, int* __restrict__ cur,
                            int* __restrict__ send, float* __restrict__ Yc,
                            float* __restrict__ fc, int E) {
  int e = blockIdx.x * blockDim.x + threadIdx.x;
  if (e >= E) return;
  int s = ei[e], r = ei[E + e];
  float dx = pos[r * 3 + 0] - pos[s * 3 + 0] + shifts[e * 3 + 0];
  float dy = pos[r * 3 + 1] - pos[s * 3 + 1] + shifts[e * 3 + 1];
  float dz = pos[r * 3 + 2] - pos[s * 3 + 2] + shifts[e * 3 + 2];
  float rr = sqrtf(dx * dx + dy * dy + dz * dz + 1e-12f);
  if (rr >= 5.0f) return;  // inactive edge: cutoff=0 -> R=0 -> msg=0
  int p = off[r] + atomicAdd(&cur[r], 1);
  if (p >= ECAP) return;  // statistically impossible; memory-safety guard
  send[p] = s;
  float ir = 1.f / rr;
  float x = dx * ir, y = dy * ir, z = dz * ir;
  const float s3 = 1.73205080757f, s5 = 2.23606797750f, s15 = 3.87298334621f;
  const float c70 = 2.09165006634f;   // sqrt(70)/4
  const float c105 = 10.2469507660f;  // sqrt(105)
  const float c42 = 1.62018517460f;   // sqrt(42)/4
  const float c7 = 1.32287565553f;    // sqrt(7)/2
  float* Yp = Yc + (size_t)p * 16;
  float xx = x * x, yy = y * y, zz = z * z;
  Yp[0] = 1.f;
  Yp[1] = s3 * x;
  Yp[2] = s3 * y;
  Yp[3] = s3 * z;
  Yp[4] = s15 * x * y;
  Yp[5] = s15 * y * z;
  Yp[6] = 0.5f * s5 * (3.f * zz - 1.f);
  Yp[7] = s15 * x * z;
  Yp[8] = 0.5f * s15 * (xx - yy);
  Yp[9] = c70 * y * (3.f * xx - yy);
  Yp[10] = c105 * x * y * z;
  Yp[11] = c42 * y * (5.f * zz - 1.f);
  Yp[12] = c7 * z * (5.f * zz - 3.f);
  Yp[13] = c42 * x * (5.f * zz - 1.f);
  Yp[14] = 0.5f * c105 * z * (xx - yy);
  Yp[15] = c70 * x * (xx - 3.f * yy);
  float xr = rr * 0.2f;
  float xr2 = xr * xr, xr4 = xr2 * xr2;
  float xr5 = xr4 * xr, xr6 = xr5 * xr, xr7 = xr6 * xr;
  float poly = 1.f - 21.f * xr5 + 35.f * xr6 - 15.f * xr7;
  float pref = 0.632455532034f /* sqrt(2/5) */ * ir * poly;
  float* fp = fc + (size_t)p * 8;
  // sin(n*pi*xr) via recurrence: s_{n+1} = 2*cos(pi*xr)*s_n - s_{n-1}
  float s1 = sinf(PI_F * xr), c1 = cosf(PI_F * xr);
  float sm = 0.f, sp2 = s1;
  fp[0] = pref * s1;
#pragma unroll
  for (int nb = 2; nb <= 8; ++nb) {
    float sn = 2.f * c1 * sp2 - sm;
    fp[nb - 1] = pref * sn;
    sm = sp2;
    sp2 = sn;
  }
}

// ---------------------------------------------------------------- MLP L1-L3
#define ATILE 256  // edges per block tile

// 64->64 GEMM: a[8e][4c] += X[k][e-oct] * W[k][c-quad], K=64
__device__ __forceinline__ void gemm64(const float* __restrict__ sW,
                                       const float* __restrict__ sX,
                                       int ebase, int cbase, float a[8][4]) {
#pragma unroll
  for (int j = 0; j < 8; ++j)
#pragma unroll
    for (int i = 0; i < 4; ++i) a[j][i] = 0.f;
#pragma unroll 4
  for (int k = 0; k < 64; ++k) {
    float4 x0 = *(const float4*)&sX[k * ATILE + ebase];
    float4 x1 = *(const float4*)&sX[k * ATILE + ebase + 4];
    float4 w = *(const float4*)&sW[k * 64 + cbase];
    float xs[8] = {x0.x, x0.y, x0.z, x0.w, x1.x, x1.y, x1.z, x1.w};
    float ws[4] = {w.x, w.y, w.z, w.w};
#pragma unroll
    for (int j = 0; j < 8; ++j)
#pragma unroll
      for (int i = 0; i < 4; ++i) a[j][i] += xs[j] * ws[i];
  }
}

__global__ __launch_bounds__(512, 2) void mlp123_k(
    const float* __restrict__ fc, const float* __restrict__ Wr1,
    const float* __restrict__ Wr2, const float* __restrict__ Wr3,
    const int* __restrict__ nact_p, float* __restrict__ act3, int layer) {
  __shared__ __attribute__((aligned(16))) float sX[64 * ATILE];  // 64 KB [k][e]
  __shared__ __attribute__((aligned(16))) float sW1[8 * 64];
  __shared__ __attribute__((aligned(16))) float sW2[64 * 64];
  __shared__ __attribute__((aligned(16))) float sW3[64 * 64];
  int nact = min(*nact_p, ECAP);
  int t0 = blockIdx.x * ATILE;
  if (t0 >= nact || nact == 0) return;
  int tid = threadIdx.x;
  {
    const float* w1 = Wr1 + (size_t)layer * 512;
    const float* w2 = Wr2 + (size_t)layer * 4096;
    const float* w3 = Wr3 + (size_t)layer * 4096;
    if (tid < 512) sW1[tid] = w1[tid];
    for (int i = tid; i < 4096; i += 512) {
      sW2[i] = w2[i];
      sW3[i] = w3[i];
    }
    // stage fc -> sX[k][e], k<8
    for (int i = tid; i < ATILE * 8; i += 512) {
      int el = i >> 3, k = i & 7;
      int e = min(t0 + el, nact - 1);
      sX[k * ATILE + el] = fc[(size_t)e * 8 + k];
    }
  }
  __syncthreads();

  int wid = tid >> 6, lane = tid & 63;
  int es = (wid >> 1) * 64;        // e-stripe base within tile
  int ch = (wid & 1) * 32;         // c-half
  int g = lane >> 3, q = lane & 7;
  int ebase = es + g * 8;
  int cbase = ch + q * 4;

  float y[8][4];
  // ---- L1: k = 0..7
  {
    float a[8][4];
#pragma unroll
    for (int j = 0; j < 8; ++j)
#pragma unroll
      for (int i = 0; i < 4; ++i) a[j][i] = 0.f;
#pragma unroll
    for (int k = 0; k < 8; ++k) {
      float4 x0 = *(const float4*)&sX[k * ATILE + ebase];
      float4 x1 = *(const float4*)&sX[k * ATILE + ebase + 4];
      float4 w = *(const float4*)&sW1[k * 64 + cbase];
      float xs[8] = {x0.x, x0.y, x0.z, x0.w, x1.x, x1.y, x1.z, x1.w};
      float ws[4] = {w.x, w.y, w.z, w.w};
#pragma unroll
      for (int j = 0; j < 8; ++j)
#pragma unroll
        for (int i = 0; i < 4; ++i) a[j][i] += xs[j] * ws[i];
    }
#pragma unroll
    for (int j = 0; j < 8; ++j)
#pragma unroll
      for (int i = 0; i < 4; ++i) y[j][i] = silu_f(a[j][i]);
  }
  __syncthreads();
#pragma unroll
  for (int i = 0; i < 4; ++i) {
    float4 v0 = {y[0][i], y[1][i], y[2][i], y[3][i]};
    float4 v1 = {y[4][i], y[5][i], y[6][i], y[7][i]};
    *(float4*)&sX[(cbase + i) * ATILE + ebase] = v0;
    *(float4*)&sX[(cbase + i) * ATILE + ebase + 4] = v1;
  }
  __syncthreads();
  // ---- L2
  {
    float a[8][4];
    gemm64(sW2, sX, ebase, cbase, a);
#pragma unroll
    for (int j = 0; j < 8; ++j)
#pragma unroll
      for (int i = 0; i < 4; ++i) y[j][i] = silu_f(a[j][i]);
  }
  __syncthreads();
#pragma unroll
  for (int i = 0; i < 4; ++i) {
    float4 v0 = {y[0][i], y[1][i], y[2][i], y[3][i]};
    float4 v1 = {y[4][i], y[5][i], y[6][i], y[7][i]};
    *(float4*)&sX[(cbase + i) * ATILE + ebase] = v0;
    *(float4*)&sX[(cbase + i) * ATILE + ebase + 4] = v1;
  }
  __syncthreads();
  // ---- L3 -> act3 (global)
  {
    float a[8][4];
    gemm64(sW3, sX, ebase, cbase, a);
#pragma unroll
    for (int j = 0; j < 8; ++j) {
      int eg = t0 + ebase + j;
      if (eg < nact) {
        float4 v = {silu_f(a[j][0]), silu_f(a[j][1]), silu_f(a[j][2]),
                    silu_f(a[j][3])};
        *(float4*)&act3[(size_t)eg * 64 + cbase] = v;
      }
    }
  }
}

// ---------------------------------------------------------------- node layer
// Fused L4 + message accumulation + node update + readout.
__global__ __launch_bounds__(512, 4) void node_gather_k(
    const float* __restrict__ h_in, float* __restrict__ h_out,
    const float* __restrict__ act3, const float* __restrict__ Wr4,
    const float* __restrict__ Wsc, const float* __restrict__ Wp,
    const float* __restrict__ Wread, const float* __restrict__ Yc,
    const int* __restrict__ send, const int* __restrict__ off,
    const int* __restrict__ spec, const int* __restrict__ batch,
    float* __restrict__ energy, const int* __restrict__ nact_p, int N, int NE,
    int layer) {
  // W4 transposed [c=256][k=64], k-quads XOR-swizzled by (c&7)
  __shared__ __attribute__((aligned(16))) float sW4[256 * 64];  // 64 KB
  __shared__ __attribute__((aligned(16))) float sVec[8][64];
  int tid = threadIdx.x;
  {
    const float* w4 = Wr4 + (size_t)layer * 16384;
    for (int i = tid; i < 16384; i += 512) {
      int k = i >> 8, c = i & 255;  // w4 is [k][c]
      sW4[c * 64 + 4 * ((k >> 2) ^ (c & 7)) + (k & 3)] = w4[i];
    }
  }
  __syncthreads();

  int wid = tid >> 6, lane = tid & 63;
  int n = blockIdx.x * 8 + wid;
  if (n >= N) return;

  int base = off[n];
  int deg = off[n + 1] - base;
  float acc[16];
#pragma unroll
  for (int i = 0; i < 16; ++i) acc[i] = 0.f;

  for (int bb = 0; bb < deg; bb += 4) {
    int m = min(4, deg - bb);
    int eu[4];
    float x[4], hs[4];
#pragma unroll
    for (int j = 0; j < 4; ++j) {
      int e = base + bb + (j < m ? j : m - 1);
      eu[j] = __builtin_amdgcn_readfirstlane(e);
      x[j] = act3[(size_t)eu[j] * 64 + lane];
      int se = send[eu[j]];
      hs[j] = h_in[(size_t)se * 64 + lane];
    }
    // L4: R[j][l] = sum_k x_j[k] * W4[k][l*64+lane]
    float R[4][4];
#pragma unroll
    for (int j = 0; j < 4; ++j)
#pragma unroll
      for (int l = 0; l < 4; ++l) R[j][l] = 0.f;
#pragma unroll
    for (int qq = 0; qq < 16; ++qq) {
      float4 wl[4];
#pragma unroll
      for (int l = 0; l < 4; ++l)
        wl[l] = *(const float4*)&sW4[(l * 64 + lane) * 64 +
                                     4 * (qq ^ (lane & 7))];
#pragma unroll
      for (int j = 0; j < 4; ++j) {
        float xa0 = __shfl(x[j], 4 * qq + 0);
        float xa1 = __shfl(x[j], 4 * qq + 1);
        float xa2 = __shfl(x[j], 4 * qq + 2);
        float xa3 = __shfl(x[j], 4 * qq + 3);
#pragma unroll
        for (int l = 0; l < 4; ++l)
          R[j][l] += xa0 * wl[l].x + xa1 * wl[l].y + xa2 * wl[l].z +
                     xa3 * wl[l].w;
      }
    }
    // messages
#pragma unroll
    for (int j = 0; j < 4; ++j) {
      if (j < m) {  // wave-uniform
        const float* yr = Yc + (size_t)eu[j] * 16;  // uniform -> s_load
        float t0_ = hs[j] * R[j][0], t1_ = hs[j] * R[j][1];
        float t2_ = hs[j] * R[j][2], t3_ = hs[j] * R[j][3];
        acc[0] += yr[0] * t0_;
        acc[1] += yr[1] * t1_;   acc[2] += yr[2] * t1_;
        acc[3] += yr[3] * t1_;
        acc[4] += yr[4] * t2_;   acc[5] += yr[5] * t2_;
        acc[6] += yr[6] * t2_;   acc[7] += yr[7] * t2_;
        acc[8] += yr[8] * t2_;
        acc[9] += yr[9] * t3_;   acc[10] += yr[10] * t3_;
        acc[11] += yr[11] * t3_; acc[12] += yr[12] * t3_;
        acc[13] += yr[13] * t3_; acc[14] += yr[14] * t3_;
        acc[15] += yr[15] * t3_;
      }
    }
  }

  // node update: inv = A0 + sum_lm A^2   (A = acc / 16)
  float inv = acc[0] * 0.0625f;
#pragma unroll
  for (int i = 0; i < 16; ++i) {
    float a2 = acc[i] * 0.0625f;
    inv += a2 * a2;
  }
  float* sv = sVec[wid];
  sv[lane] = inv;
  LDSFENCE();
  int sp = spec[n];
  const float* wsc = Wsc + ((size_t)layer * NE + sp) * 4096;
  const float* wp = Wp + (size_t)layer * 4096;
  const float* hold = h_in + (size_t)n * 64;
  float hv = 0.f;
#pragma unroll 4
  for (int k = 0; k < 64; ++k) {
    hv += sv[k] * wp[k * 64 + lane];
    hv += hold[k] * wsc[k * 64 + lane];
  }
  h_out[(size_t)n * 64 + lane] = hv;
  LDSFENCE();
  sv[lane] = hv;
  LDSFENCE();
  if (lane < 3) {
    const float* wr = Wread + (size_t)layer * 64 * 3;
    float s = 0.f;
#pragma unroll 8
    for (int d = 0; d < 64; ++d) s += sv[d] * wr[d * 3 + lane];
    atomicAdd(&energy[batch[n] * 3 + lane], s);
  }
}

// ---------------------------------------------------------------- output
__global__ void write_out_k(const float* __restrict__ energy,
                            float* __restrict__ out, int n) {
  int i = threadIdx.x;
  if (i < n) out[i] = energy[i];
}

// ---------------------------------------------------------------- host
extern "C" void kernel_launch(void* const* d_in, const int* in_sizes, int n_in,
                              void* d_out, int out_size, void* d_ws,
                              size_t ws_size, hipStream_t stream) {
  const float* pos = (const float*)d_in[0];
  const float* shifts = (const float*)d_in[1];
  const float* attrs = (const float*)d_in[2];
  const float* ae = (const float*)d_in[3];
  const float* Wemb = (const float*)d_in[4];
  const float* Wr1 = (const float*)d_in[5];
  const float* Wr2 = (const float*)d_in[6];
  const float* Wr3 = (const float*)d_in[7];
  const float* Wr4 = (const float*)d_in[8];
  const float* Wsc = (const float*)d_in[9];
  const float* Wp = (const float*)d_in[10];
  const float* Wrd = (const float*)d_in[11];
  const int* ei = (const int*)d_in[12];
  const int* batch = (const int*)d_in[13];

  int N = in_sizes[0] / 3;
  int E = in_sizes[12] / 2;
  int NE = in_sizes[3];
  int nlayer = in_sizes[5] / (8 * 64);

  char* w = (char*)d_ws;
  auto alloc = [&](size_t bytes) {
    void* p = (void*)w;
    w += (bytes + 255) & ~(size_t)255;
    return p;
  };
  float* h0 = (float*)alloc((size_t)N * 64 * 4);
  float* h1 = (float*)alloc((size_t)N * 64 * 4);
  float* Yc = (float*)alloc((size_t)ECAP * 16 * 4);
  float* fc = (float*)alloc((size_t)ECAP * 8 * 4);
  float* act3 = (float*)alloc((size_t)ECAP * 64 * 4);
  int* send = (int*)alloc((size_t)ECAP * 4);
  int* off = (int*)alloc((size_t)(N + 1) * 4);
  int* deg = (int*)alloc((size_t)N * 4);
  int* cur = (int*)alloc((size_t)N * 4);
  int* spec = (int*)alloc((size_t)N * 4);
  float* energy = (float*)alloc(64 * 4);

  hipMemsetAsync(deg, 0, (size_t)N * 4, stream);
  hipMemsetAsync(cur, 0, (size_t)N * 4, stream);
  hipMemsetAsync(energy, 0, 64 * 4, stream);

  node_init_k<<<(N + 3) / 4, 256, 0, stream>>>(attrs, ae, Wemb, batch, h0, spec,
                                               energy, N, NE);
  edge_count_k<<<(E + 255) / 256, 256, 0, stream>>>(pos, shifts, ei, deg, E);
  scan_deg_k<<<1, 1024, 0, stream>>>(deg, off, N);
  edge_fill_k<<<(E + 255) / 256, 256, 0, stream>>>(pos, shifts, ei, off, cur,
                                                   send, Yc, fc, E);
  const int* nact_p = off + N;
  float* hin = h0;
  float* hout = h1;
  int mgrid = (E + ATILE - 1) / ATILE;
  for (int l = 0; l < nlayer; ++l) {
    mlp123_k<<<mgrid, 512, 0, stream>>>(fc, Wr1, Wr2, Wr3, nact_p, act3, l);
    node_gather_k<<<(N + 7) / 8, 512, 0, stream>>>(
        hin, hout, act3, Wr4, Wsc, Wp, Wrd, Yc, send, off, spec, batch, energy,
        nact_p, N, NE, l);
    float* t = hin;
    hin = hout;
    hout = t;
  }
  write_out_k<<<1, 64, 0, stream>>>(energy, (float*)d_out, out_size);
}

// Round 6
// 460.949 us; speedup vs baseline: 9.8830x; 9.8830x over previous
//
#include <hip/hip_runtime.h>
#include <math.h>
#include <stdint.h>

// EMACE forward, f32.
// R6 structure: ALL GEMM-shaped work edge-parallel; node kernel is pure
// streaming accumulate + update.
//  1) node_init, edge CSR build (count/scan/fill)
//  2) per layer:
//     a) mlp123_k: L1+L2+L3 (8x8-blocked f32 GEMM, 256-edge tiles) -> act3
//     b) mlp4_k:   L4 64->256 GEMM (128-edge tiles, 8ex8c blocking) -> Rbuf
//     c) gather_node_k: per-node wave streams edges: acc[lm] += Y*hs*R,
//        then inv/W_prod/W_sc update + readout. No weights, no spills.
//  3) write_out

#define PI_F 3.14159265358979323846f
#define ECAP_MAX 72000  // active-edge capacity (expected ~45k)

__device__ __forceinline__ float silu_f(float x) { return x / (1.f + __expf(-x)); }

#define LDSFENCE() asm volatile("s_waitcnt lgkmcnt(0)" ::: "memory")

// ---------------------------------------------------------------- node init
__global__ void node_init_k(const float* __restrict__ attrs,
                            const float* __restrict__ ae,
                            const float* __restrict__ Wemb,
                            const int* __restrict__ batch,
                            float* __restrict__ h0, int* __restrict__ spec,
                            float* __restrict__ energy, int N, int NE) {
  int n = (int)((blockIdx.x * blockDim.x + threadIdx.x) >> 6);
  int lane = threadIdx.x & 63;
  if (n >= N) return;
  const float* a = attrs + (size_t)n * NE;
  int sp = 0;
  for (int e = 0; e < NE; ++e)
    if (a[e] > 0.5f) sp = e;
  h0[(size_t)n * 64 + lane] = Wemb[sp * 64 + lane];
  if (lane == 0) spec[n] = sp;
  if (lane < 3) atomicAdd(&energy[batch[n] * 3 + lane], ae[sp]);
}

// ---------------------------------------------------------------- edge pass 1
__global__ void edge_count_k(const float* __restrict__ pos,
                             const float* __restrict__ shifts,
                             const int* __restrict__ ei,
                             int* __restrict__ deg, int E) {
  int e = blockIdx.x * blockDim.x + threadIdx.x;
  if (e >= E) return;
  int s = ei[e], r = ei[E + e];
  float dx = pos[r * 3 + 0] - pos[s * 3 + 0] + shifts[e * 3 + 0];
  float dy = pos[r * 3 + 1] - pos[s * 3 + 1] + shifts[e * 3 + 1];
  float dz = pos[r * 3 + 2] - pos[s * 3 + 2] + shifts[e * 3 + 2];
  float d2 = dx * dx + dy * dy + dz * dz;
  if (d2 < 25.0f) atomicAdd(&deg[r], 1);
}

// ---------------------------------------------------------------- scan
__global__ void scan_deg_k(const int* __restrict__ deg, int* __restrict__ off,
                           int N) {
  __shared__ int sdat[1024];
  int tid = threadIdx.x;
  int chunk = (N + 1023) / 1024;
  int s0 = tid * chunk, s1 = min(s0 + chunk, N);
  int s = 0;
  for (int i = s0; i < s1; ++i) s += deg[i];
  sdat[tid] = s;
  __syncthreads();
  for (int d = 1; d < 1024; d <<= 1) {
    int v = (tid >= d) ? sdat[tid - d] : 0;
    __syncthreads();
    sdat[tid] += v;
    __syncthreads();
  }
  int run = sdat[tid] - s;  // exclusive prefix
  for (int i = s0; i < s1; ++i) {
    off[i] = run;
    run += deg[i];
  }
  if (tid == 1023) off[N] = sdat[1023];
}

// ---------------------------------------------------------------- edge pass 2
__global__ void edge_fill_k(const float* __restrict__ pos,
                            const float* __restrict__ shifts,
                            const int* __restrict__ ei,
                            const int* __restrict__ off, int* __restrict__ cur,
                            int* __restrict__ send, float* __restrict__ Yc,
                            float* __restrict__ fc, int E, int ecap) {
  int e = blockIdx.x * blockDim.x + threadIdx.x;
  if (e >= E) return;
  int s = ei[e], r = ei[E + e];
  float dx = pos[r * 3 + 0] - pos[s * 3 + 0] + shifts[e * 3 + 0];
  float dy = pos[r * 3 + 1] - pos[s * 3 + 1] + shifts[e * 3 + 1];
  float dz = pos[r * 3 + 2] - pos[s * 3 + 2] + shifts[e * 3 + 2];
  float rr = sqrtf(dx * dx + dy * dy + dz * dz + 1e-12f);
  if (rr >= 5.0f) return;  // inactive edge: cutoff=0 -> R=0 -> msg=0
  int p = off[r] + atomicAdd(&cur[r], 1);
  if (p >= ecap) return;  // statistically impossible; memory-safety guard
  send[p] = s;
  float ir = 1.f / rr;
  float x = dx * ir, y = dy * ir, z = dz * ir;
  const float s3 = 1.73205080757f, s5 = 2.23606797750f, s15 = 3.87298334621f;
  const float c70 = 2.09165006634f;   // sqrt(70)/4
  const float c105 = 10.2469507660f;  // sqrt(105)
  const float c42 = 1.62018517460f;   // sqrt(42)/4
  const float c7 = 1.32287565553f;    // sqrt(7)/2
  float* Yp = Yc + (size_t)p * 16;
  float xx = x * x, yy = y * y, zz = z * z;
  Yp[0] = 1.f;
  Yp[1] = s3 * x;
  Yp[2] = s3 * y;
  Yp[3] = s3 * z;
  Yp[4] = s15 * x * y;
  Yp[5] = s15 * y * z;
  Yp[6] = 0.5f * s5 * (3.f * zz - 1.f);
  Yp[7] = s15 * x * z;
  Yp[8] = 0.5f * s15 * (xx - yy);
  Yp[9] = c70 * y * (3.f * xx - yy);
  Yp[10] = c105 * x * y * z;
  Yp[11] = c42 * y * (5.f * zz - 1.f);
  Yp[12] = c7 * z * (5.f * zz - 3.f);
  Yp[13] = c42 * x * (5.f * zz - 1.f);
  Yp[14] = 0.5f * c105 * z * (xx - yy);
  Yp[15] = c70 * x * (xx - 3.f * yy);
  float xr = rr * 0.2f;
  float xr2 = xr * xr, xr4 = xr2 * xr2;
  float xr5 = xr4 * xr, xr6 = xr5 * xr, xr7 = xr6 * xr;
  float poly = 1.f - 21.f * xr5 + 35.f * xr6 - 15.f * xr7;
  float pref = 0.632455532034f /* sqrt(2/5) */ * ir * poly;
  float* fp = fc + (size_t)p * 8;
  // sin(n*pi*xr) via recurrence: s_{n+1} = 2*cos(pi*xr)*s_n - s_{n-1}
  float s1 = sinf(PI_F * xr), c1 = cosf(PI_F * xr);
  float sm = 0.f, sp2 = s1;
  fp[0] = pref * s1;
#pragma unroll
  for (int nb = 2; nb <= 8; ++nb) {
    float sn = 2.f * c1 * sp2 - sm;
    fp[nb - 1] = pref * sn;
    sm = sp2;
    sp2 = sn;
  }
}

// ---------------------------------------------------------------- MLP L1-L3
#define ATILE 256  // edges per block tile

__device__ __forceinline__ void gemm64(const float* __restrict__ sW,
                                       const float* __restrict__ sX,
                                       int ebase, int cbase, float a[8][4]) {
#pragma unroll
  for (int j = 0; j < 8; ++j)
#pragma unroll
    for (int i = 0; i < 4; ++i) a[j][i] = 0.f;
#pragma unroll 4
  for (int k = 0; k < 64; ++k) {
    float4 x0 = *(const float4*)&sX[k * ATILE + ebase];
    float4 x1 = *(const float4*)&sX[k * ATILE + ebase + 4];
    float4 w = *(const float4*)&sW[k * 64 + cbase];
    float xs[8] = {x0.x, x0.y, x0.z, x0.w, x1.x, x1.y, x1.z, x1.w};
    float ws[4] = {w.x, w.y, w.z, w.w};
#pragma unroll
    for (int j = 0; j < 8; ++j)
#pragma unroll
      for (int i = 0; i < 4; ++i) a[j][i] += xs[j] * ws[i];
  }
}

__global__ __launch_bounds__(512, 2) void mlp123_k(
    const float* __restrict__ fc, const float* __restrict__ Wr1,
    const float* __restrict__ Wr2, const float* __restrict__ Wr3,
    const int* __restrict__ nact_p, float* __restrict__ act3, int layer,
    int ecap) {
  __shared__ __attribute__((aligned(16))) float sX[64 * ATILE];  // 64 KB [k][e]
  __shared__ __attribute__((aligned(16))) float sW1[8 * 64];
  __shared__ __attribute__((aligned(16))) float sW2[64 * 64];
  __shared__ __attribute__((aligned(16))) float sW3[64 * 64];
  int nact = min(*nact_p, ecap);
  int t0 = blockIdx.x * ATILE;
  if (t0 >= nact || nact == 0) return;
  int tid = threadIdx.x;
  {
    const float* w1 = Wr1 + (size_t)layer * 512;
    const float* w2 = Wr2 + (size_t)layer * 4096;
    const float* w3 = Wr3 + (size_t)layer * 4096;
    if (tid < 512) sW1[tid] = w1[tid];
    for (int i = tid; i < 4096; i += 512) {
      sW2[i] = w2[i];
      sW3[i] = w3[i];
    }
    for (int i = tid; i < ATILE * 8; i += 512) {
      int el = i >> 3, k = i & 7;
      int e = min(t0 + el, nact - 1);
      sX[k * ATILE + el] = fc[(size_t)e * 8 + k];
    }
  }
  __syncthreads();

  int wid = tid >> 6, lane = tid & 63;
  int es = (wid >> 1) * 64;
  int ch = (wid & 1) * 32;
  int g = lane >> 3, q = lane & 7;
  int ebase = es + g * 8;
  int cbase = ch + q * 4;

  float y[8][4];
  // ---- L1: k = 0..7
  {
    float a[8][4];
#pragma unroll
    for (int j = 0; j < 8; ++j)
#pragma unroll
      for (int i = 0; i < 4; ++i) a[j][i] = 0.f;
#pragma unroll
    for (int k = 0; k < 8; ++k) {
      float4 x0 = *(const float4*)&sX[k * ATILE + ebase];
      float4 x1 = *(const float4*)&sX[k * ATILE + ebase + 4];
      float4 w = *(const float4*)&sW1[k * 64 + cbase];
      float xs[8] = {x0.x, x0.y, x0.z, x0.w, x1.x, x1.y, x1.z, x1.w};
      float ws[4] = {w.x, w.y, w.z, w.w};
#pragma unroll
      for (int j = 0; j < 8; ++j)
#pragma unroll
        for (int i = 0; i < 4; ++i) a[j][i] += xs[j] * ws[i];
    }
#pragma unroll
    for (int j = 0; j < 8; ++j)
#pragma unroll
      for (int i = 0; i < 4; ++i) y[j][i] = silu_f(a[j][i]);
  }
  __syncthreads();
#pragma unroll
  for (int i = 0; i < 4; ++i) {
    float4 v0 = {y[0][i], y[1][i], y[2][i], y[3][i]};
    float4 v1 = {y[4][i], y[5][i], y[6][i], y[7][i]};
    *(float4*)&sX[(cbase + i) * ATILE + ebase] = v0;
    *(float4*)&sX[(cbase + i) * ATILE + ebase + 4] = v1;
  }
  __syncthreads();
  // ---- L2
  {
    float a[8][4];
    gemm64(sW2, sX, ebase, cbase, a);
#pragma unroll
    for (int j = 0; j < 8; ++j)
#pragma unroll
      for (int i = 0; i < 4; ++i) y[j][i] = silu_f(a[j][i]);
  }
  __syncthreads();
#pragma unroll
  for (int i = 0; i < 4; ++i) {
    float4 v0 = {y[0][i], y[1][i], y[2][i], y[3][i]};
    float4 v1 = {y[4][i], y[5][i], y[6][i], y[7][i]};
    *(float4*)&sX[(cbase + i) * ATILE + ebase] = v0;
    *(float4*)&sX[(cbase + i) * ATILE + ebase + 4] = v1;
  }
  __syncthreads();
  // ---- L3 -> act3 (global)
  {
    float a[8][4];
    gemm64(sW3, sX, ebase, cbase, a);
#pragma unroll
    for (int j = 0; j < 8; ++j) {
      int eg = t0 + ebase + j;
      if (eg < nact) {
        float4 v = {silu_f(a[j][0]), silu_f(a[j][1]), silu_f(a[j][2]),
                    silu_f(a[j][3])};
        *(float4*)&act3[(size_t)eg * 64 + cbase] = v;
      }
    }
  }
}

// ---------------------------------------------------------------- MLP L4
#define MT 128  // edges per tile
#define SXS (MT + 4)  // padded row stride (528 B, 16B-aligned)

__global__ __launch_bounds__(512, 1) void mlp4_k(
    const float* __restrict__ act3, const float* __restrict__ Wr4,
    const int* __restrict__ nact_p, float* __restrict__ Rbuf, int layer,
    int ecap) {
  __shared__ __attribute__((aligned(16))) float sX[64 * SXS];   // ~34 KB [k][e]
  __shared__ __attribute__((aligned(16))) float sW4[64 * 256];  // 64 KB [k][c]
  int nact = min(*nact_p, ecap);
  int t0 = blockIdx.x * MT;
  if (t0 >= nact || nact == 0) return;
  int tid = threadIdx.x;
  {
    const float* w4 = Wr4 + (size_t)layer * 16384;
    for (int i = tid; i < 16384; i += 512) sW4[i] = w4[i];
    for (int i = tid; i < MT * 64; i += 512) {
      int el = i >> 6, k = i & 63;
      int e = min(t0 + el, nact - 1);
      sX[k * SXS + el] = act3[(size_t)e * 64 + k];
    }
  }
  __syncthreads();

  int egrp = tid >> 5;  // 0..15, 8 edges each
  int cgrp = tid & 31;  // 0..31, 8 cols each
  int eb = egrp * 8, cb = cgrp * 8;
  float a[8][8];
#pragma unroll
  for (int j = 0; j < 8; ++j)
#pragma unroll
    for (int i = 0; i < 8; ++i) a[j][i] = 0.f;
#pragma unroll 2
  for (int k = 0; k < 64; ++k) {
    float4 x0 = *(const float4*)&sX[k * SXS + eb];
    float4 x1 = *(const float4*)&sX[k * SXS + eb + 4];
    float4 w0 = *(const float4*)&sW4[k * 256 + cb];
    float4 w1 = *(const float4*)&sW4[k * 256 + cb + 4];
    float xs[8] = {x0.x, x0.y, x0.z, x0.w, x1.x, x1.y, x1.z, x1.w};
    float ws[8] = {w0.x, w0.y, w0.z, w0.w, w1.x, w1.y, w1.z, w1.w};
#pragma unroll
    for (int j = 0; j < 8; ++j)
#pragma unroll
      for (int i = 0; i < 8; ++i) a[j][i] += xs[j] * ws[i];
  }
#pragma unroll
  for (int j = 0; j < 8; ++j) {
    int eg = t0 + eb + j;
    if (eg < nact) {
      float4 v0 = {a[j][0], a[j][1], a[j][2], a[j][3]};
      float4 v1 = {a[j][4], a[j][5], a[j][6], a[j][7]};
      *(float4*)&Rbuf[(size_t)eg * 256 + cb] = v0;
      *(float4*)&Rbuf[(size_t)eg * 256 + cb + 4] = v1;
    }
  }
}

// ---------------------------------------------------------------- node layer
// Streams per-edge (R, hs, Y), accumulates acc[16], then node update+readout.
__global__ __launch_bounds__(256) void gather_node_k(
    const float* __restrict__ h_in, float* __restrict__ h_out,
    const float* __restrict__ Rbuf, const float* __restrict__ Wsc,
    const float* __restrict__ Wp, const float* __restrict__ Wread,
    const float* __restrict__ Yc, const int* __restrict__ send,
    const int* __restrict__ off, const int* __restrict__ spec,
    const int* __restrict__ batch, float* __restrict__ energy, int N, int NE,
    int layer) {
  __shared__ __attribute__((aligned(16))) float sVec[4][64];
  int tid = threadIdx.x;
  int wid = tid >> 6, lane = tid & 63;
  int n = blockIdx.x * 4 + wid;
  if (n >= N) return;

  int base = off[n];
  int deg = off[n + 1] - base;
  float acc[16];
#pragma unroll
  for (int i = 0; i < 16; ++i) acc[i] = 0.f;

  for (int b = 0; b < deg; b += 2) {
    int m = min(2, deg - b);
    int e0 = __builtin_amdgcn_readfirstlane(base + b);
    int e1 = __builtin_amdgcn_readfirstlane(base + b + (m - 1));
    int s0 = send[e0], s1 = send[e1];
    float hs0 = h_in[(size_t)s0 * 64 + lane];
    float hs1 = h_in[(size_t)s1 * 64 + lane];
    float r0[4], r1[4];
#pragma unroll
    for (int l = 0; l < 4; ++l) {
      r0[l] = Rbuf[(size_t)e0 * 256 + l * 64 + lane];
      r1[l] = Rbuf[(size_t)e1 * 256 + l * 64 + lane];
    }
    const float* y0 = Yc + (size_t)e0 * 16;  // uniform -> s_loads
    {
      float t0_ = hs0 * r0[0], t1_ = hs0 * r0[1];
      float t2_ = hs0 * r0[2], t3_ = hs0 * r0[3];
      acc[0] += y0[0] * t0_;
      acc[1] += y0[1] * t1_;   acc[2] += y0[2] * t1_;   acc[3] += y0[3] * t1_;
      acc[4] += y0[4] * t2_;   acc[5] += y0[5] * t2_;   acc[6] += y0[6] * t2_;
      acc[7] += y0[7] * t2_;   acc[8] += y0[8] * t2_;
      acc[9] += y0[9] * t3_;   acc[10] += y0[10] * t3_; acc[11] += y0[11] * t3_;
      acc[12] += y0[12] * t3_; acc[13] += y0[13] * t3_; acc[14] += y0[14] * t3_;
      acc[15] += y0[15] * t3_;
    }
    if (m > 1) {  // wave-uniform
      const float* y1 = Yc + (size_t)e1 * 16;
      float t0_ = hs1 * r1[0], t1_ = hs1 * r1[1];
      float t2_ = hs1 * r1[2], t3_ = hs1 * r1[3];
      acc[0] += y1[0] * t0_;
      acc[1] += y1[1] * t1_;   acc[2] += y1[2] * t1_;   acc[3] += y1[3] * t1_;
      acc[4] += y1[4] * t2_;   acc[5] += y1[5] * t2_;   acc[6] += y1[6] * t2_;
      acc[7] += y1[7] * t2_;   acc[8] += y1[8] * t2_;
      acc[9] += y1[9] * t3_;   acc[10] += y1[10] * t3_; acc[11] += y1[11] * t3_;
      acc[12] += y1[12] * t3_; acc[13] += y1[13] * t3_; acc[14] += y1[14] * t3_;
      acc[15] += y1[15] * t3_;
    }
  }

  // node update: inv = A0 + sum_lm A^2   (A = acc / 16)
  float inv = acc[0] * 0.0625f;
#pragma unroll
  for (int i = 0; i < 16; ++i) {
    float a2 = acc[i] * 0.0625f;
    inv += a2 * a2;
  }
  float* sv = sVec[wid];
  sv[lane] = inv;
  LDSFENCE();
  int sp = spec[n];
  const float* wsc = Wsc + ((size_t)layer * NE + sp) * 4096;
  const float* wp = Wp + (size_t)layer * 4096;
  const float* hold = h_in + (size_t)n * 64;
  float hv = 0.f;
#pragma unroll 4
  for (int k = 0; k < 64; ++k) {
    hv += sv[k] * wp[k * 64 + lane];
    hv += hold[k] * wsc[k * 64 + lane];
  }
  h_out[(size_t)n * 64 + lane] = hv;
  LDSFENCE();
  sv[lane] = hv;
  LDSFENCE();
  if (lane < 3) {
    const float* wr = Wread + (size_t)layer * 64 * 3;
    float s = 0.f;
#pragma unroll 8
    for (int d = 0; d < 64; ++d) s += sv[d] * wr[d * 3 + lane];
    atomicAdd(&energy[batch[n] * 3 + lane], s);
  }
}

// ---------------------------------------------------------------- output
__global__ void write_out_k(const float* __restrict__ energy,
                            float* __restrict__ out, int n) {
  int i = threadIdx.x;
  if (i < n) out[i] = energy[i];
}

// ---------------------------------------------------------------- host
extern "C" void kernel_launch(void* const* d_in, const int* in_sizes, int n_in,
                              void* d_out, int out_size, void* d_ws,
                              size_t ws_size, hipStream_t stream) {
  const float* pos = (const float*)d_in[0];
  const float* shifts = (const float*)d_in[1];
  const float* attrs = (const float*)d_in[2];
  const float* ae = (const float*)d_in[3];
  const float* Wemb = (const float*)d_in[4];
  const float* Wr1 = (const float*)d_in[5];
  const float* Wr2 = (const float*)d_in[6];
  const float* Wr3 = (const float*)d_in[7];
  const float* Wr4 = (const float*)d_in[8];
  const float* Wsc = (const float*)d_in[9];
  const float* Wp = (const float*)d_in[10];
  const float* Wrd = (const float*)d_in[11];
  const int* ei = (const int*)d_in[12];
  const int* batch = (const int*)d_in[13];

  int N = in_sizes[0] / 3;
  int E = in_sizes[12] / 2;
  int NE = in_sizes[3];
  int nlayer = in_sizes[5] / (8 * 64);

  // adaptive edge capacity: fixed ~6 MB + 1380 B per edge
  size_t fixed = (size_t)N * 64 * 4 * 2 + (size_t)N * 4 * 4 + (1 << 20);
  int ecap = (int)((ws_size > fixed ? ws_size - fixed : 0) / 1380);
  if (ecap > ECAP_MAX) ecap = ECAP_MAX;

  char* w = (char*)d_ws;
  auto alloc = [&](size_t bytes) {
    void* p = (void*)w;
    w += (bytes + 255) & ~(size_t)255;
    return p;
  };
  float* h0 = (float*)alloc((size_t)N * 64 * 4);
  float* h1 = (float*)alloc((size_t)N * 64 * 4);
  float* Yc = (float*)alloc((size_t)ecap * 16 * 4);
  float* fc = (float*)alloc((size_t)ecap * 8 * 4);
  float* act3 = (float*)alloc((size_t)ecap * 64 * 4);
  float* Rbuf = (float*)alloc((size_t)ecap * 256 * 4);
  int* send = (int*)alloc((size_t)ecap * 4);
  int* off = (int*)alloc((size_t)(N + 1) * 4);
  int* deg = (int*)alloc((size_t)N * 4);
  int* cur = (int*)alloc((size_t)N * 4);
  int* spec = (int*)alloc((size_t)N * 4);
  float* energy = (float*)alloc(64 * 4);

  hipMemsetAsync(deg, 0, (size_t)N * 4, stream);
  hipMemsetAsync(cur, 0, (size_t)N * 4, stream);
  hipMemsetAsync(energy, 0, 64 * 4, stream);

  node_init_k<<<(N + 3) / 4, 256, 0, stream>>>(attrs, ae, Wemb, batch, h0, spec,
                                               energy, N, NE);
  edge_count_k<<<(E + 255) / 256, 256, 0, stream>>>(pos, shifts, ei, deg, E);
  scan_deg_k<<<1, 1024, 0, stream>>>(deg, off, N);
  edge_fill_k<<<(E + 255) / 256, 256, 0, stream>>>(pos, shifts, ei, off, cur,
                                                   send, Yc, fc, E, ecap);
  const int* nact_p = off + N;
  float* hin = h0;
  float* hout = h1;
  for (int l = 0; l < nlayer; ++l) {
    mlp123_k<<<(E + ATILE - 1) / ATILE, 512, 0, stream>>>(fc, Wr1, Wr2, Wr3,
                                                          nact_p, act3, l, ecap);
    mlp4_k<<<(E + MT - 1) / MT, 512, 0, stream>>>(act3, Wr4, nact_p, Rbuf, l,
                                                  ecap);
    gather_node_k<<<(N + 3) / 4, 256, 0, stream>>>(
        hin, hout, Rbuf, Wsc, Wp, Wrd, Yc, send, off, spec, batch, energy, N,
        NE, l);
    float* t = hin;
    hin = hout;
    hout = t;
  }
  write_out_k<<<1, 64, 0, stream>>>(energy, (float*)d_out, out_size);
}

// Round 7
// 445.471 us; speedup vs baseline: 10.2264x; 1.0347x over previous
//
#include <hip/hip_runtime.h>
#include <math.h>
#include <stdint.h>

// EMACE forward, f32.
// R7 changes vs R6:
//  - gather_node_k: explicit 4-edge load-phase ILP, 8 waves/block,
//    Wp staged in LDS, launch_bounds(512,2) (cap 128 VGPR; R6's 20-VGPR
//    serial schedule was the latency bound).
//  - mlp4_k: W4 staged in 2 column halves -> 66 KB LDS -> 2 blocks/CU.

#define PI_F 3.14159265358979323846f
#define ECAP_MAX 72000  // active-edge capacity (expected ~45k)

__device__ __forceinline__ float silu_f(float x) { return x / (1.f + __expf(-x)); }

#define LDSFENCE() asm volatile("s_waitcnt lgkmcnt(0)" ::: "memory")

// ---------------------------------------------------------------- node init
__global__ void node_init_k(const float* __restrict__ attrs,
                            const float* __restrict__ ae,
                            const float* __restrict__ Wemb,
                            const int* __restrict__ batch,
                            float* __restrict__ h0, int* __restrict__ spec,
                            float* __restrict__ energy, int N, int NE) {
  int n = (int)((blockIdx.x * blockDim.x + threadIdx.x) >> 6);
  int lane = threadIdx.x & 63;
  if (n >= N) return;
  const float* a = attrs + (size_t)n * NE;
  int sp = 0;
  for (int e = 0; e < NE; ++e)
    if (a[e] > 0.5f) sp = e;
  h0[(size_t)n * 64 + lane] = Wemb[sp * 64 + lane];
  if (lane == 0) spec[n] = sp;
  if (lane < 3) atomicAdd(&energy[batch[n] * 3 + lane], ae[sp]);
}

// ---------------------------------------------------------------- edge pass 1
__global__ void edge_count_k(const float* __restrict__ pos,
                             const float* __restrict__ shifts,
                             const int* __restrict__ ei,
                             int* __restrict__ deg, int E) {
  int e = blockIdx.x * blockDim.x + threadIdx.x;
  if (e >= E) return;
  int s = ei[e], r = ei[E + e];
  float dx = pos[r * 3 + 0] - pos[s * 3 + 0] + shifts[e * 3 + 0];
  float dy = pos[r * 3 + 1] - pos[s * 3 + 1] + shifts[e * 3 + 1];
  float dz = pos[r * 3 + 2] - pos[s * 3 + 2] + shifts[e * 3 + 2];
  float d2 = dx * dx + dy * dy + dz * dz;
  if (d2 < 25.0f) atomicAdd(&deg[r], 1);
}

// ---------------------------------------------------------------- scan
__global__ void scan_deg_k(const int* __restrict__ deg, int* __restrict__ off,
                           int N) {
  __shared__ int sdat[1024];
  int tid = threadIdx.x;
  int chunk = (N + 1023) / 1024;
  int s0 = tid * chunk, s1 = min(s0 + chunk, N);
  int s = 0;
  for (int i = s0; i < s1; ++i) s += deg[i];
  sdat[tid] = s;
  __syncthreads();
  for (int d = 1; d < 1024; d <<= 1) {
    int v = (tid >= d) ? sdat[tid - d] : 0;
    __syncthreads();
    sdat[tid] += v;
    __syncthreads();
  }
  int run = sdat[tid] - s;  // exclusive prefix
  for (int i = s0; i < s1; ++i) {
    off[i] = run;
    run += deg[i];
  }
  if (tid == 1023) off[N] = sdat[1023];
}

// ---------------------------------------------------------------- edge pass 2
__global__ void edge_fill_k(const float* __restrict__ pos,
                            const float* __restrict__ shifts,
                            const int* __restrict__ ei,
                            const int* __restrict__ off, int* __restrict__ cur,
                            int* __restrict__ send, float* __restrict__ Yc,
                            float* __restrict__ fc, int E, int ecap) {
  int e = blockIdx.x * blockDim.x + threadIdx.x;
  if (e >= E) return;
  int s = ei[e], r = ei[E + e];
  float dx = pos[r * 3 + 0] - pos[s * 3 + 0] + shifts[e * 3 + 0];
  float dy = pos[r * 3 + 1] - pos[s * 3 + 1] + shifts[e * 3 + 1];
  float dz = pos[r * 3 + 2] - pos[s * 3 + 2] + shifts[e * 3 + 2];
  float rr = sqrtf(dx * dx + dy * dy + dz * dz + 1e-12f);
  if (rr >= 5.0f) return;  // inactive edge: cutoff=0 -> R=0 -> msg=0
  int p = off[r] + atomicAdd(&cur[r], 1);
  if (p >= ecap) return;  // statistically impossible; memory-safety guard
  send[p] = s;
  float ir = 1.f / rr;
  float x = dx * ir, y = dy * ir, z = dz * ir;
  const float s3 = 1.73205080757f, s5 = 2.23606797750f, s15 = 3.87298334621f;
  const float c70 = 2.09165006634f;   // sqrt(70)/4
  const float c105 = 10.2469507660f;  // sqrt(105)
  const float c42 = 1.62018517460f;   // sqrt(42)/4
  const float c7 = 1.32287565553f;    // sqrt(7)/2
  float* Yp = Yc + (size_t)p * 16;
  float xx = x * x, yy = y * y, zz = z * z;
  Yp[0] = 1.f;
  Yp[1] = s3 * x;
  Yp[2] = s3 * y;
  Yp[3] = s3 * z;
  Yp[4] = s15 * x * y;
  Yp[5] = s15 * y * z;
  Yp[6] = 0.5f * s5 * (3.f * zz - 1.f);
  Yp[7] = s15 * x * z;
  Yp[8] = 0.5f * s15 * (xx - yy);
  Yp[9] = c70 * y * (3.f * xx - yy);
  Yp[10] = c105 * x * y * z;
  Yp[11] = c42 * y * (5.f * zz - 1.f);
  Yp[12] = c7 * z * (5.f * zz - 3.f);
  Yp[13] = c42 * x * (5.f * zz - 1.f);
  Yp[14] = 0.5f * c105 * z * (xx - yy);
  Yp[15] = c70 * x * (xx - 3.f * yy);
  float xr = rr * 0.2f;
  float xr2 = xr * xr, xr4 = xr2 * xr2;
  float xr5 = xr4 * xr, xr6 = xr5 * xr, xr7 = xr6 * xr;
  float poly = 1.f - 21.f * xr5 + 35.f * xr6 - 15.f * xr7;
  float pref = 0.632455532034f /* sqrt(2/5) */ * ir * poly;
  float* fp = fc + (size_t)p * 8;
  // sin(n*pi*xr) via recurrence: s_{n+1} = 2*cos(pi*xr)*s_n - s_{n-1}
  float s1 = sinf(PI_F * xr), c1 = cosf(PI_F * xr);
  float sm = 0.f, sp2 = s1;
  fp[0] = pref * s1;
#pragma unroll
  for (int nb = 2; nb <= 8; ++nb) {
    float sn = 2.f * c1 * sp2 - sm;
    fp[nb - 1] = pref * sn;
    sm = sp2;
    sp2 = sn;
  }
}

// ---------------------------------------------------------------- MLP L1-L3
#define ATILE 256  // edges per block tile

__device__ __forceinline__ void gemm64(const float* __restrict__ sW,
                                       const float* __restrict__ sX,
                                       int ebase, int cbase, float a[8][4]) {
#pragma unroll
  for (int j = 0; j < 8; ++j)
#pragma unroll
    for (int i = 0; i < 4; ++i) a[j][i] = 0.f;
#pragma unroll 4
  for (int k = 0; k < 64; ++k) {
    float4 x0 = *(const float4*)&sX[k * ATILE + ebase];
    float4 x1 = *(const float4*)&sX[k * ATILE + ebase + 4];
    float4 w = *(const float4*)&sW[k * 64 + cbase];
    float xs[8] = {x0.x, x0.y, x0.z, x0.w, x1.x, x1.y, x1.z, x1.w};
    float ws[4] = {w.x, w.y, w.z, w.w};
#pragma unroll
    for (int j = 0; j < 8; ++j)
#pragma unroll
      for (int i = 0; i < 4; ++i) a[j][i] += xs[j] * ws[i];
  }
}

__global__ __launch_bounds__(512, 2) void mlp123_k(
    const float* __restrict__ fc, const float* __restrict__ Wr1,
    const float* __restrict__ Wr2, const float* __restrict__ Wr3,
    const int* __restrict__ nact_p, float* __restrict__ act3, int layer,
    int ecap) {
  __shared__ __attribute__((aligned(16))) float sX[64 * ATILE];  // 64 KB [k][e]
  __shared__ __attribute__((aligned(16))) float sW1[8 * 64];
  __shared__ __attribute__((aligned(16))) float sW2[64 * 64];
  __shared__ __attribute__((aligned(16))) float sW3[64 * 64];
  int nact = min(*nact_p, ecap);
  int t0 = blockIdx.x * ATILE;
  if (t0 >= nact || nact == 0) return;
  int tid = threadIdx.x;
  {
    const float* w1 = Wr1 + (size_t)layer * 512;
    const float* w2 = Wr2 + (size_t)layer * 4096;
    const float* w3 = Wr3 + (size_t)layer * 4096;
    if (tid < 512) sW1[tid] = w1[tid];
    for (int i = tid; i < 4096; i += 512) {
      sW2[i] = w2[i];
      sW3[i] = w3[i];
    }
    for (int i = tid; i < ATILE * 8; i += 512) {
      int el = i >> 3, k = i & 7;
      int e = min(t0 + el, nact - 1);
      sX[k * ATILE + el] = fc[(size_t)e * 8 + k];
    }
  }
  __syncthreads();

  int wid = tid >> 6, lane = tid & 63;
  int es = (wid >> 1) * 64;
  int ch = (wid & 1) * 32;
  int g = lane >> 3, q = lane & 7;
  int ebase = es + g * 8;
  int cbase = ch + q * 4;

  float y[8][4];
  // ---- L1: k = 0..7
  {
    float a[8][4];
#pragma unroll
    for (int j = 0; j < 8; ++j)
#pragma unroll
      for (int i = 0; i < 4; ++i) a[j][i] = 0.f;
#pragma unroll
    for (int k = 0; k < 8; ++k) {
      float4 x0 = *(const float4*)&sX[k * ATILE + ebase];
      float4 x1 = *(const float4*)&sX[k * ATILE + ebase + 4];
      float4 w = *(const float4*)&sW1[k * 64 + cbase];
      float xs[8] = {x0.x, x0.y, x0.z, x0.w, x1.x, x1.y, x1.z, x1.w};
      float ws[4] = {w.x, w.y, w.z, w.w};
#pragma unroll
      for (int j = 0; j < 8; ++j)
#pragma unroll
        for (int i = 0; i < 4; ++i) a[j][i] += xs[j] * ws[i];
    }
#pragma unroll
    for (int j = 0; j < 8; ++j)
#pragma unroll
      for (int i = 0; i < 4; ++i) y[j][i] = silu_f(a[j][i]);
  }
  __syncthreads();
#pragma unroll
  for (int i = 0; i < 4; ++i) {
    float4 v0 = {y[0][i], y[1][i], y[2][i], y[3][i]};
    float4 v1 = {y[4][i], y[5][i], y[6][i], y[7][i]};
    *(float4*)&sX[(cbase + i) * ATILE + ebase] = v0;
    *(float4*)&sX[(cbase + i) * ATILE + ebase + 4] = v1;
  }
  __syncthreads();
  // ---- L2
  {
    float a[8][4];
    gemm64(sW2, sX, ebase, cbase, a);
#pragma unroll
    for (int j = 0; j < 8; ++j)
#pragma unroll
      for (int i = 0; i < 4; ++i) y[j][i] = silu_f(a[j][i]);
  }
  __syncthreads();
#pragma unroll
  for (int i = 0; i < 4; ++i) {
    float4 v0 = {y[0][i], y[1][i], y[2][i], y[3][i]};
    float4 v1 = {y[4][i], y[5][i], y[6][i], y[7][i]};
    *(float4*)&sX[(cbase + i) * ATILE + ebase] = v0;
    *(float4*)&sX[(cbase + i) * ATILE + ebase + 4] = v1;
  }
  __syncthreads();
  // ---- L3 -> act3 (global)
  {
    float a[8][4];
    gemm64(sW3, sX, ebase, cbase, a);
#pragma unroll
    for (int j = 0; j < 8; ++j) {
      int eg = t0 + ebase + j;
      if (eg < nact) {
        float4 v = {silu_f(a[j][0]), silu_f(a[j][1]), silu_f(a[j][2]),
                    silu_f(a[j][3])};
        *(float4*)&act3[(size_t)eg * 64 + cbase] = v;
      }
    }
  }
}

// ---------------------------------------------------------------- MLP L4
#define MT 128        // edges per tile
#define SXS (MT + 4)  // padded row stride

// 64->256 GEMM in two 128-column halves: LDS 33.8+32 = 66 KB -> 2 blocks/CU.
__global__ __launch_bounds__(512, 1) void mlp4_k(
    const float* __restrict__ act3, const float* __restrict__ Wr4,
    const int* __restrict__ nact_p, float* __restrict__ Rbuf, int layer,
    int ecap) {
  __shared__ __attribute__((aligned(16))) float sX[64 * SXS];   // 33.8 KB [k][e]
  __shared__ __attribute__((aligned(16))) float sW[64 * 128];   // 32 KB [k][chalf]
  int nact = min(*nact_p, ecap);
  int t0 = blockIdx.x * MT;
  if (t0 >= nact || nact == 0) return;
  int tid = threadIdx.x;
  const float* w4 = Wr4 + (size_t)layer * 16384;
  for (int i = tid; i < MT * 64; i += 512) {
    int el = i >> 6, k = i & 63;
    int e = min(t0 + el, nact - 1);
    sX[k * SXS + el] = act3[(size_t)e * 64 + k];
  }
  int egrp = tid >> 5;  // 0..15 -> 8 edges each
  int cgrp = tid & 31;  // 0..31 -> 4 cols each (within half)
  int eb = egrp * 8, cb = cgrp * 4;
#pragma unroll
  for (int half = 0; half < 2; ++half) {
    __syncthreads();  // sX ready (h0) / prev compute done (h1)
    for (int i = tid; i < 8192; i += 512) {
      int k = i >> 7, cc = i & 127;
      sW[k * 128 + cc] = w4[k * 256 + half * 128 + cc];
    }
    __syncthreads();
    float a[8][4];
#pragma unroll
    for (int j = 0; j < 8; ++j)
#pragma unroll
      for (int i = 0; i < 4; ++i) a[j][i] = 0.f;
#pragma unroll 4
    for (int k = 0; k < 64; ++k) {
      float4 x0 = *(const float4*)&sX[k * SXS + eb];
      float4 x1 = *(const float4*)&sX[k * SXS + eb + 4];
      float4 w = *(const float4*)&sW[k * 128 + cb];
      float xs[8] = {x0.x, x0.y, x0.z, x0.w, x1.x, x1.y, x1.z, x1.w};
      float ws[4] = {w.x, w.y, w.z, w.w};
#pragma unroll
      for (int j = 0; j < 8; ++j)
#pragma unroll
        for (int i = 0; i < 4; ++i) a[j][i] += xs[j] * ws[i];
    }
#pragma unroll
    for (int j = 0; j < 8; ++j) {
      int eg = t0 + eb + j;
      if (eg < nact) {
        float4 v = {a[j][0], a[j][1], a[j][2], a[j][3]};
        *(float4*)&Rbuf[(size_t)eg * 256 + half * 128 + cb] = v;
      }
    }
  }
}

// ---------------------------------------------------------------- node layer
// Streams per-edge (R, hs, Y) with 4-edge load-phase ILP, accumulates
// acc[16], then node update (Wp from LDS) + readout.
__global__ __launch_bounds__(512, 2) void gather_node_k(
    const float* __restrict__ h_in, float* __restrict__ h_out,
    const float* __restrict__ Rbuf, const float* __restrict__ Wsc,
    const float* __restrict__ Wp, const float* __restrict__ Wread,
    const float* __restrict__ Yc, const int* __restrict__ send,
    const int* __restrict__ off, const int* __restrict__ spec,
    const int* __restrict__ batch, float* __restrict__ energy, int N, int NE,
    int layer) {
  __shared__ __attribute__((aligned(16))) float sWp[4096];  // 16 KB
  __shared__ __attribute__((aligned(16))) float sVec[8][64];
  int tid = threadIdx.x;
  {
    const float* wp = Wp + (size_t)layer * 4096;
    for (int i = tid; i < 4096; i += 512) sWp[i] = wp[i];
  }
  __syncthreads();
  int wid = tid >> 6, lane = tid & 63;
  int n = blockIdx.x * 8 + wid;
  if (n >= N) return;

  int base = off[n];
  int deg = off[n + 1] - base;
  float acc[16];
#pragma unroll
  for (int i = 0; i < 16; ++i) acc[i] = 0.f;

  for (int b = 0; b < deg; b += 4) {
    int m = min(4, deg - b);
    int eu[4];
    float hs[4], r[4][4];
    // ---- load phase: 20 independent vector loads in flight
#pragma unroll
    for (int j = 0; j < 4; ++j) {
      int e = base + b + (j < m ? j : m - 1);
      eu[j] = __builtin_amdgcn_readfirstlane(e);
      hs[j] = h_in[(size_t)send[eu[j]] * 64 + lane];
#pragma unroll
      for (int l = 0; l < 4; ++l)
        r[j][l] = Rbuf[(size_t)eu[j] * 256 + l * 64 + lane];
    }
    // ---- compute phase
#pragma unroll
    for (int j = 0; j < 4; ++j) {
      if (j < m) {  // wave-uniform
        const float* yp = Yc + (size_t)eu[j] * 16;  // uniform -> s_loads
        float t0_ = hs[j] * r[j][0], t1_ = hs[j] * r[j][1];
        float t2_ = hs[j] * r[j][2], t3_ = hs[j] * r[j][3];
        acc[0] += yp[0] * t0_;
        acc[1] += yp[1] * t1_;   acc[2] += yp[2] * t1_;   acc[3] += yp[3] * t1_;
        acc[4] += yp[4] * t2_;   acc[5] += yp[5] * t2_;   acc[6] += yp[6] * t2_;
        acc[7] += yp[7] * t2_;   acc[8] += yp[8] * t2_;
        acc[9] += yp[9] * t3_;   acc[10] += yp[10] * t3_;
        acc[11] += yp[11] * t3_; acc[12] += yp[12] * t3_;
        acc[13] += yp[13] * t3_; acc[14] += yp[14] * t3_;
        acc[15] += yp[15] * t3_;
      }
    }
  }

  // node update: inv = A0 + sum_lm A^2   (A = acc / 16)
  float inv = acc[0] * 0.0625f;
#pragma unroll
  for (int i = 0; i < 16; ++i) {
    float a2 = acc[i] * 0.0625f;
    inv += a2 * a2;
  }
  float* sv = sVec[wid];
  sv[lane] = inv;
  LDSFENCE();
  int sp = spec[n];
  const float* wsc = Wsc + ((size_t)layer * NE + sp) * 4096;
  const float* hold = h_in + (size_t)n * 64;
  float hv = 0.f;
#pragma unroll 4
  for (int k = 0; k < 64; ++k) {
    hv += sv[k] * sWp[k * 64 + lane];
    hv += hold[k] * wsc[k * 64 + lane];
  }
  h_out[(size_t)n * 64 + lane] = hv;
  LDSFENCE();
  sv[lane] = hv;
  LDSFENCE();
  if (lane < 3) {
    const float* wr = Wread + (size_t)layer * 64 * 3;
    float s = 0.f;
#pragma unroll 8
    for (int d = 0; d < 64; ++d) s += sv[d] * wr[d * 3 + lane];
    atomicAdd(&energy[batch[n] * 3 + lane], s);
  }
}

// ---------------------------------------------------------------- output
__global__ void write_out_k(const float* __restrict__ energy,
                            float* __restrict__ out, int n) {
  int i = threadIdx.x;
  if (i < n) out[i] = energy[i];
}

// ---------------------------------------------------------------- host
extern "C" void kernel_launch(void* const* d_in, const int* in_sizes, int n_in,
                              void* d_out, int out_size, void* d_ws,
                              size_t ws_size, hipStream_t stream) {
  const float* pos = (const float*)d_in[0];
  const float* shifts = (const float*)d_in[1];
  const float* attrs = (const float*)d_in[2];
  const float* ae = (const float*)d_in[3];
  const float* Wemb = (const float*)d_in[4];
  const float* Wr1 = (const float*)d_in[5];
  const float* Wr2 = (const float*)d_in[6];
  const float* Wr3 = (const float*)d_in[7];
  const float* Wr4 = (const float*)d_in[8];
  const float* Wsc = (const float*)d_in[9];
  const float* Wp = (const float*)d_in[10];
  const float* Wrd = (const float*)d_in[11];
  const int* ei = (const int*)d_in[12];
  const int* batch = (const int*)d_in[13];

  int N = in_sizes[0] / 3;
  int E = in_sizes[12] / 2;
  int NE = in_sizes[3];
  int nlayer = in_sizes[5] / (8 * 64);

  // adaptive edge capacity: fixed ~6 MB + 1380 B per edge
  size_t fixed = (size_t)N * 64 * 4 * 2 + (size_t)N * 4 * 4 + (1 << 20);
  int ecap = (int)((ws_size > fixed ? ws_size - fixed : 0) / 1380);
  if (ecap > ECAP_MAX) ecap = ECAP_MAX;

  char* w = (char*)d_ws;
  auto alloc = [&](size_t bytes) {
    void* p = (void*)w;
    w += (bytes + 255) & ~(size_t)255;
    return p;
  };
  float* h0 = (float*)alloc((size_t)N * 64 * 4);
  float* h1 = (float*)alloc((size_t)N * 64 * 4);
  float* Yc = (float*)alloc((size_t)ecap * 16 * 4);
  float* fc = (float*)alloc((size_t)ecap * 8 * 4);
  float* act3 = (float*)alloc((size_t)ecap * 64 * 4);
  float* Rbuf = (float*)alloc((size_t)ecap * 256 * 4);
  int* send = (int*)alloc((size_t)ecap * 4);
  int* off = (int*)alloc((size_t)(N + 1) * 4);
  int* deg = (int*)alloc((size_t)N * 4);
  int* cur = (int*)alloc((size_t)N * 4);
  int* spec = (int*)alloc((size_t)N * 4);
  float* energy = (float*)alloc(64 * 4);

  hipMemsetAsync(deg, 0, (size_t)N * 4, stream);
  hipMemsetAsync(cur, 0, (size_t)N * 4, stream);
  hipMemsetAsync(energy, 0, 64 * 4, stream);

  node_init_k<<<(N + 3) / 4, 256, 0, stream>>>(attrs, ae, Wemb, batch, h0, spec,
                                               energy, N, NE);
  edge_count_k<<<(E + 255) / 256, 256, 0, stream>>>(pos, shifts, ei, deg, E);
  scan_deg_k<<<1, 1024, 0, stream>>>(deg, off, N);
  edge_fill_k<<<(E + 255) / 256, 256, 0, stream>>>(pos, shifts, ei, off, cur,
                                                   send, Yc, fc, E, ecap);
  const int* nact_p = off + N;
  float* hin = h0;
  float* hout = h1;
  for (int l = 0; l < nlayer; ++l) {
    mlp123_k<<<(E + ATILE - 1) / ATILE, 512, 0, stream>>>(fc, Wr1, Wr2, Wr3,
                                                          nact_p, act3, l, ecap);
    mlp4_k<<<(E + MT - 1) / MT, 512, 0, stream>>>(act3, Wr4, nact_p, Rbuf, l,
                                                  ecap);
    gather_node_k<<<(N + 7) / 8, 512, 0, stream>>>(
        hin, hout, Rbuf, Wsc, Wp, Wrd, Yc, send, off, spec, batch, energy, N,
        NE, l);
    float* t = hin;
    hin = hout;
    hout = t;
  }
  write_out_k<<<1, 64, 0, stream>>>(energy, (float*)d_out, out_size);
}

// Round 8
// 224.825 us; speedup vs baseline: 20.2628x; 1.9814x over previous
//
#include <hip/hip_runtime.h>
#include <math.h>
#include <stdint.h>

// EMACE forward, f32.
// R8 changes vs R7:
//  - NO energy atomics anywhere: node_init -> node_e0[n]; gather_node_k
//    accumulates per-node readout into eread[n][4]; reduce_energy_k
//    (1 block/graph, tree reduce) writes d_out directly. R7's 101us
//    gather was dominated by same-address atomic serialization
//    (sorted batch -> ~625 nodes/graph hitting one f32 address).
//  - mlp4_k: launch_bounds(512,2) so 66 KB LDS runs 2 blocks/CU.

#define PI_F 3.14159265358979323846f
#define ECAP_MAX 72000  // active-edge capacity (expected ~45k)

__device__ __forceinline__ float silu_f(float x) { return x / (1.f + __expf(-x)); }

#define LDSFENCE() asm volatile("s_waitcnt lgkmcnt(0)" ::: "memory")

// ---------------------------------------------------------------- node init
__global__ void node_init_k(const float* __restrict__ attrs,
                            const float* __restrict__ ae,
                            const float* __restrict__ Wemb,
                            float* __restrict__ h0, int* __restrict__ spec,
                            float* __restrict__ node_e0, int N, int NE) {
  int n = (int)((blockIdx.x * blockDim.x + threadIdx.x) >> 6);
  int lane = threadIdx.x & 63;
  if (n >= N) return;
  const float* a = attrs + (size_t)n * NE;
  int sp = 0;
  for (int e = 0; e < NE; ++e)
    if (a[e] > 0.5f) sp = e;
  h0[(size_t)n * 64 + lane] = Wemb[sp * 64 + lane];
  if (lane == 0) {
    spec[n] = sp;
    node_e0[n] = ae[sp];
  }
}

// ---------------------------------------------------------------- edge pass 1
__global__ void edge_count_k(const float* __restrict__ pos,
                             const float* __restrict__ shifts,
                             const int* __restrict__ ei,
                             int* __restrict__ deg, int E) {
  int e = blockIdx.x * blockDim.x + threadIdx.x;
  if (e >= E) return;
  int s = ei[e], r = ei[E + e];
  float dx = pos[r * 3 + 0] - pos[s * 3 + 0] + shifts[e * 3 + 0];
  float dy = pos[r * 3 + 1] - pos[s * 3 + 1] + shifts[e * 3 + 1];
  float dz = pos[r * 3 + 2] - pos[s * 3 + 2] + shifts[e * 3 + 2];
  float d2 = dx * dx + dy * dy + dz * dz;
  if (d2 < 25.0f) atomicAdd(&deg[r], 1);
}

// ---------------------------------------------------------------- scan
__global__ void scan_deg_k(const int* __restrict__ deg, int* __restrict__ off,
                           int N) {
  __shared__ int sdat[1024];
  int tid = threadIdx.x;
  int chunk = (N + 1023) / 1024;
  int s0 = tid * chunk, s1 = min(s0 + chunk, N);
  int s = 0;
  for (int i = s0; i < s1; ++i) s += deg[i];
  sdat[tid] = s;
  __syncthreads();
  for (int d = 1; d < 1024; d <<= 1) {
    int v = (tid >= d) ? sdat[tid - d] : 0;
    __syncthreads();
    sdat[tid] += v;
    __syncthreads();
  }
  int run = sdat[tid] - s;  // exclusive prefix
  for (int i = s0; i < s1; ++i) {
    off[i] = run;
    run += deg[i];
  }
  if (tid == 1023) off[N] = sdat[1023];
}

// ---------------------------------------------------------------- edge pass 2
__global__ void edge_fill_k(const float* __restrict__ pos,
                            const float* __restrict__ shifts,
                            const int* __restrict__ ei,
                            const int* __restrict__ off, int* __restrict__ cur,
                            int* __restrict__ send, float* __restrict__ Yc,
                            float* __restrict__ fc, int E, int ecap) {
  int e = blockIdx.x * blockDim.x + threadIdx.x;
  if (e >= E) return;
  int s = ei[e], r = ei[E + e];
  float dx = pos[r * 3 + 0] - pos[s * 3 + 0] + shifts[e * 3 + 0];
  float dy = pos[r * 3 + 1] - pos[s * 3 + 1] + shifts[e * 3 + 1];
  float dz = pos[r * 3 + 2] - pos[s * 3 + 2] + shifts[e * 3 + 2];
  float rr = sqrtf(dx * dx + dy * dy + dz * dz + 1e-12f);
  if (rr >= 5.0f) return;  // inactive edge: cutoff=0 -> R=0 -> msg=0
  int p = off[r] + atomicAdd(&cur[r], 1);
  if (p >= ecap) return;  // statistically impossible; memory-safety guard
  send[p] = s;
  float ir = 1.f / rr;
  float x = dx * ir, y = dy * ir, z = dz * ir;
  const float s3 = 1.73205080757f, s5 = 2.23606797750f, s15 = 3.87298334621f;
  const float c70 = 2.09165006634f;   // sqrt(70)/4
  const float c105 = 10.2469507660f;  // sqrt(105)
  const float c42 = 1.62018517460f;   // sqrt(42)/4
  const float c7 = 1.32287565553f;    // sqrt(7)/2
  float* Yp = Yc + (size_t)p * 16;
  float xx = x * x, yy = y * y, zz = z * z;
  Yp[0] = 1.f;
  Yp[1] = s3 * x;
  Yp[2] = s3 * y;
  Yp[3] = s3 * z;
  Yp[4] = s15 * x * y;
  Yp[5] = s15 * y * z;
  Yp[6] = 0.5f * s5 * (3.f * zz - 1.f);
  Yp[7] = s15 * x * z;
  Yp[8] = 0.5f * s15 * (xx - yy);
  Yp[9] = c70 * y * (3.f * xx - yy);
  Yp[10] = c105 * x * y * z;
  Yp[11] = c42 * y * (5.f * zz - 1.f);
  Yp[12] = c7 * z * (5.f * zz - 3.f);
  Yp[13] = c42 * x * (5.f * zz - 1.f);
  Yp[14] = 0.5f * c105 * z * (xx - yy);
  Yp[15] = c70 * x * (xx - 3.f * yy);
  float xr = rr * 0.2f;
  float xr2 = xr * xr, xr4 = xr2 * xr2;
  float xr5 = xr4 * xr, xr6 = xr5 * xr, xr7 = xr6 * xr;
  float poly = 1.f - 21.f * xr5 + 35.f * xr6 - 15.f * xr7;
  float pref = 0.632455532034f /* sqrt(2/5) */ * ir * poly;
  float* fp = fc + (size_t)p * 8;
  // sin(n*pi*xr) via recurrence: s_{n+1} = 2*cos(pi*xr)*s_n - s_{n-1}
  float s1 = sinf(PI_F * xr), c1 = cosf(PI_F * xr);
  float sm = 0.f, sp2 = s1;
  fp[0] = pref * s1;
#pragma unroll
  for (int nb = 2; nb <= 8; ++nb) {
    float sn = 2.f * c1 * sp2 - sm;
    fp[nb - 1] = pref * sn;
    sm = sp2;
    sp2 = sn;
  }
}

// ---------------------------------------------------------------- MLP L1-L3
#define ATILE 256  // edges per block tile

__device__ __forceinline__ void gemm64(const float* __restrict__ sW,
                                       const float* __restrict__ sX,
                                       int ebase, int cbase, float a[8][4]) {
#pragma unroll
  for (int j = 0; j < 8; ++j)
#pragma unroll
    for (int i = 0; i < 4; ++i) a[j][i] = 0.f;
#pragma unroll 4
  for (int k = 0; k < 64; ++k) {
    float4 x0 = *(const float4*)&sX[k * ATILE + ebase];
    float4 x1 = *(const float4*)&sX[k * ATILE + ebase + 4];
    float4 w = *(const float4*)&sW[k * 64 + cbase];
    float xs[8] = {x0.x, x0.y, x0.z, x0.w, x1.x, x1.y, x1.z, x1.w};
    float ws[4] = {w.x, w.y, w.z, w.w};
#pragma unroll
    for (int j = 0; j < 8; ++j)
#pragma unroll
      for (int i = 0; i < 4; ++i) a[j][i] += xs[j] * ws[i];
  }
}

__global__ __launch_bounds__(512, 2) void mlp123_k(
    const float* __restrict__ fc, const float* __restrict__ Wr1,
    const float* __restrict__ Wr2, const float* __restrict__ Wr3,
    const int* __restrict__ nact_p, float* __restrict__ act3, int layer,
    int ecap) {
  __shared__ __attribute__((aligned(16))) float sX[64 * ATILE];  // 64 KB [k][e]
  __shared__ __attribute__((aligned(16))) float sW1[8 * 64];
  __shared__ __attribute__((aligned(16))) float sW2[64 * 64];
  __shared__ __attribute__((aligned(16))) float sW3[64 * 64];
  int nact = min(*nact_p, ecap);
  int t0 = blockIdx.x * ATILE;
  if (t0 >= nact || nact == 0) return;
  int tid = threadIdx.x;
  {
    const float* w1 = Wr1 + (size_t)layer * 512;
    const float* w2 = Wr2 + (size_t)layer * 4096;
    const float* w3 = Wr3 + (size_t)layer * 4096;
    if (tid < 512) sW1[tid] = w1[tid];
    for (int i = tid; i < 4096; i += 512) {
      sW2[i] = w2[i];
      sW3[i] = w3[i];
    }
    for (int i = tid; i < ATILE * 8; i += 512) {
      int el = i >> 3, k = i & 7;
      int e = min(t0 + el, nact - 1);
      sX[k * ATILE + el] = fc[(size_t)e * 8 + k];
    }
  }
  __syncthreads();

  int wid = tid >> 6, lane = tid & 63;
  int es = (wid >> 1) * 64;
  int ch = (wid & 1) * 32;
  int g = lane >> 3, q = lane & 7;
  int ebase = es + g * 8;
  int cbase = ch + q * 4;

  float y[8][4];
  // ---- L1: k = 0..7
  {
    float a[8][4];
#pragma unroll
    for (int j = 0; j < 8; ++j)
#pragma unroll
      for (int i = 0; i < 4; ++i) a[j][i] = 0.f;
#pragma unroll
    for (int k = 0; k < 8; ++k) {
      float4 x0 = *(const float4*)&sX[k * ATILE + ebase];
      float4 x1 = *(const float4*)&sX[k * ATILE + ebase + 4];
      float4 w = *(const float4*)&sW1[k * 64 + cbase];
      float xs[8] = {x0.x, x0.y, x0.z, x0.w, x1.x, x1.y, x1.z, x1.w};
      float ws[4] = {w.x, w.y, w.z, w.w};
#pragma unroll
      for (int j = 0; j < 8; ++j)
#pragma unroll
        for (int i = 0; i < 4; ++i) a[j][i] += xs[j] * ws[i];
    }
#pragma unroll
    for (int j = 0; j < 8; ++j)
#pragma unroll
      for (int i = 0; i < 4; ++i) y[j][i] = silu_f(a[j][i]);
  }
  __syncthreads();
#pragma unroll
  for (int i = 0; i < 4; ++i) {
    float4 v0 = {y[0][i], y[1][i], y[2][i], y[3][i]};
    float4 v1 = {y[4][i], y[5][i], y[6][i], y[7][i]};
    *(float4*)&sX[(cbase + i) * ATILE + ebase] = v0;
    *(float4*)&sX[(cbase + i) * ATILE + ebase + 4] = v1;
  }
  __syncthreads();
  // ---- L2
  {
    float a[8][4];
    gemm64(sW2, sX, ebase, cbase, a);
#pragma unroll
    for (int j = 0; j < 8; ++j)
#pragma unroll
      for (int i = 0; i < 4; ++i) y[j][i] = silu_f(a[j][i]);
  }
  __syncthreads();
#pragma unroll
  for (int i = 0; i < 4; ++i) {
    float4 v0 = {y[0][i], y[1][i], y[2][i], y[3][i]};
    float4 v1 = {y[4][i], y[5][i], y[6][i], y[7][i]};
    *(float4*)&sX[(cbase + i) * ATILE + ebase] = v0;
    *(float4*)&sX[(cbase + i) * ATILE + ebase + 4] = v1;
  }
  __syncthreads();
  // ---- L3 -> act3 (global)
  {
    float a[8][4];
    gemm64(sW3, sX, ebase, cbase, a);
#pragma unroll
    for (int j = 0; j < 8; ++j) {
      int eg = t0 + ebase + j;
      if (eg < nact) {
        float4 v = {silu_f(a[j][0]), silu_f(a[j][1]), silu_f(a[j][2]),
                    silu_f(a[j][3])};
        *(float4*)&act3[(size_t)eg * 64 + cbase] = v;
      }
    }
  }
}

// ---------------------------------------------------------------- MLP L4
#define MT 128        // edges per tile
#define SXS (MT + 4)  // padded row stride

// 64->256 GEMM in two 128-column halves: LDS 33.8+32 = 66 KB -> 2 blocks/CU.
__global__ __launch_bounds__(512, 2) void mlp4_k(
    const float* __restrict__ act3, const float* __restrict__ Wr4,
    const int* __restrict__ nact_p, float* __restrict__ Rbuf, int layer,
    int ecap) {
  __shared__ __attribute__((aligned(16))) float sX[64 * SXS];   // 33.8 KB [k][e]
  __shared__ __attribute__((aligned(16))) float sW[64 * 128];   // 32 KB [k][chalf]
  int nact = min(*nact_p, ecap);
  int t0 = blockIdx.x * MT;
  if (t0 >= nact || nact == 0) return;
  int tid = threadIdx.x;
  const float* w4 = Wr4 + (size_t)layer * 16384;
  for (int i = tid; i < MT * 64; i += 512) {
    int el = i >> 6, k = i & 63;
    int e = min(t0 + el, nact - 1);
    sX[k * SXS + el] = act3[(size_t)e * 64 + k];
  }
  int egrp = tid >> 5;  // 0..15 -> 8 edges each
  int cgrp = tid & 31;  // 0..31 -> 4 cols each (within half)
  int eb = egrp * 8, cb = cgrp * 4;
#pragma unroll
  for (int half = 0; half < 2; ++half) {
    __syncthreads();  // sX ready (h0) / prev compute done (h1)
    for (int i = tid; i < 8192; i += 512) {
      int k = i >> 7, cc = i & 127;
      sW[k * 128 + cc] = w4[k * 256 + half * 128 + cc];
    }
    __syncthreads();
    float a[8][4];
#pragma unroll
    for (int j = 0; j < 8; ++j)
#pragma unroll
      for (int i = 0; i < 4; ++i) a[j][i] = 0.f;
#pragma unroll 4
    for (int k = 0; k < 64; ++k) {
      float4 x0 = *(const float4*)&sX[k * SXS + eb];
      float4 x1 = *(const float4*)&sX[k * SXS + eb + 4];
      float4 w = *(const float4*)&sW[k * 128 + cb];
      float xs[8] = {x0.x, x0.y, x0.z, x0.w, x1.x, x1.y, x1.z, x1.w};
      float ws[4] = {w.x, w.y, w.z, w.w};
#pragma unroll
      for (int j = 0; j < 8; ++j)
#pragma unroll
        for (int i = 0; i < 4; ++i) a[j][i] += xs[j] * ws[i];
    }
#pragma unroll
    for (int j = 0; j < 8; ++j) {
      int eg = t0 + eb + j;
      if (eg < nact) {
        float4 v = {a[j][0], a[j][1], a[j][2], a[j][3]};
        *(float4*)&Rbuf[(size_t)eg * 256 + half * 128 + cb] = v;
      }
    }
  }
}

// ---------------------------------------------------------------- node layer
// Streams per-edge (R, hs, Y) with 4-edge load-phase ILP, accumulates
// acc[16], then node update (Wp from LDS) + per-node readout (NO atomics).
__global__ __launch_bounds__(512, 2) void gather_node_k(
    const float* __restrict__ h_in, float* __restrict__ h_out,
    const float* __restrict__ Rbuf, const float* __restrict__ Wsc,
    const float* __restrict__ Wp, const float* __restrict__ Wread,
    const float* __restrict__ Yc, const int* __restrict__ send,
    const int* __restrict__ off, const int* __restrict__ spec,
    float* __restrict__ eread, int N, int NE, int layer) {
  __shared__ __attribute__((aligned(16))) float sWp[4096];  // 16 KB
  __shared__ __attribute__((aligned(16))) float sVec[8][64];
  int tid = threadIdx.x;
  {
    const float* wp = Wp + (size_t)layer * 4096;
    for (int i = tid; i < 4096; i += 512) sWp[i] = wp[i];
  }
  __syncthreads();
  int wid = tid >> 6, lane = tid & 63;
  int n = blockIdx.x * 8 + wid;
  if (n >= N) return;

  int base = off[n];
  int deg = off[n + 1] - base;
  float acc[16];
#pragma unroll
  for (int i = 0; i < 16; ++i) acc[i] = 0.f;

  for (int b = 0; b < deg; b += 4) {
    int m = min(4, deg - b);
    int eu[4];
    float hs[4], r[4][4];
    // ---- load phase: independent vector loads in flight
#pragma unroll
    for (int j = 0; j < 4; ++j) {
      int e = base + b + (j < m ? j : m - 1);
      eu[j] = __builtin_amdgcn_readfirstlane(e);
      hs[j] = h_in[(size_t)send[eu[j]] * 64 + lane];
#pragma unroll
      for (int l = 0; l < 4; ++l)
        r[j][l] = Rbuf[(size_t)eu[j] * 256 + l * 64 + lane];
    }
    // ---- compute phase
#pragma unroll
    for (int j = 0; j < 4; ++j) {
      if (j < m) {  // wave-uniform
        const float* yp = Yc + (size_t)eu[j] * 16;  // uniform -> s_loads
        float t0_ = hs[j] * r[j][0], t1_ = hs[j] * r[j][1];
        float t2_ = hs[j] * r[j][2], t3_ = hs[j] * r[j][3];
        acc[0] += yp[0] * t0_;
        acc[1] += yp[1] * t1_;   acc[2] += yp[2] * t1_;   acc[3] += yp[3] * t1_;
        acc[4] += yp[4] * t2_;   acc[5] += yp[5] * t2_;   acc[6] += yp[6] * t2_;
        acc[7] += yp[7] * t2_;   acc[8] += yp[8] * t2_;
        acc[9] += yp[9] * t3_;   acc[10] += yp[10] * t3_;
        acc[11] += yp[11] * t3_; acc[12] += yp[12] * t3_;
        acc[13] += yp[13] * t3_; acc[14] += yp[14] * t3_;
        acc[15] += yp[15] * t3_;
      }
    }
  }

  // node update: inv = A0 + sum_lm A^2   (A = acc / 16)
  float inv = acc[0] * 0.0625f;
#pragma unroll
  for (int i = 0; i < 16; ++i) {
    float a2 = acc[i] * 0.0625f;
    inv += a2 * a2;
  }
  float* sv = sVec[wid];
  sv[lane] = inv;
  LDSFENCE();
  int sp = spec[n];
  const float* wsc = Wsc + ((size_t)layer * NE + sp) * 4096;
  const float* hold = h_in + (size_t)n * 64;
  float hv = 0.f;
#pragma unroll 4
  for (int k = 0; k < 64; ++k) {
    hv += sv[k] * sWp[k * 64 + lane];
    hv += hold[k] * wsc[k * 64 + lane];
  }
  h_out[(size_t)n * 64 + lane] = hv;
  LDSFENCE();
  sv[lane] = hv;
  LDSFENCE();
  if (lane < 3) {
    const float* wr = Wread + (size_t)layer * 64 * 3;
    float s = 0.f;
#pragma unroll 8
    for (int d = 0; d < 64; ++d) s += sv[d] * wr[d * 3 + lane];
    eread[(size_t)n * 4 + lane] += s;  // private to this wave: no atomic
  }
}

// ---------------------------------------------------------------- energy out
// One block per graph: out[g][c] = sum_{n: batch[n]==g} (node_e0[n]+eread[n][c])
__global__ __launch_bounds__(256) void reduce_energy_k(
    const float* __restrict__ node_e0, const float* __restrict__ eread,
    const int* __restrict__ batch, float* __restrict__ out, int N, int G) {
  __shared__ float red[256 * 4];
  int g = blockIdx.x;
  int tid = threadIdx.x;
  float p0 = 0.f, p1 = 0.f, p2 = 0.f;
  for (int n = tid; n < N; n += 256) {
    if (batch[n] == g) {
      float e0 = node_e0[n];
      p0 += e0 + eread[(size_t)n * 4 + 0];
      p1 += e0 + eread[(size_t)n * 4 + 1];
      p2 += e0 + eread[(size_t)n * 4 + 2];
    }
  }
  red[tid * 4 + 0] = p0;
  red[tid * 4 + 1] = p1;
  red[tid * 4 + 2] = p2;
  __syncthreads();
  for (int s = 128; s > 0; s >>= 1) {
    if (tid < s) {
      red[tid * 4 + 0] += red[(tid + s) * 4 + 0];
      red[tid * 4 + 1] += red[(tid + s) * 4 + 1];
      red[tid * 4 + 2] += red[(tid + s) * 4 + 2];
    }
    __syncthreads();
  }
  if (tid < 3) out[g * 3 + tid] = red[tid];
}

// ---------------------------------------------------------------- host
extern "C" void kernel_launch(void* const* d_in, const int* in_sizes, int n_in,
                              void* d_out, int out_size, void* d_ws,
                              size_t ws_size, hipStream_t stream) {
  const float* pos = (const float*)d_in[0];
  const float* shifts = (const float*)d_in[1];
  const float* attrs = (const float*)d_in[2];
  const float* ae = (const float*)d_in[3];
  const float* Wemb = (const float*)d_in[4];
  const float* Wr1 = (const float*)d_in[5];
  const float* Wr2 = (const float*)d_in[6];
  const float* Wr3 = (const float*)d_in[7];
  const float* Wr4 = (const float*)d_in[8];
  const float* Wsc = (const float*)d_in[9];
  const float* Wp = (const float*)d_in[10];
  const float* Wrd = (const float*)d_in[11];
  const int* ei = (const int*)d_in[12];
  const int* batch = (const int*)d_in[13];

  int N = in_sizes[0] / 3;
  int E = in_sizes[12] / 2;
  int NE = in_sizes[3];
  int nlayer = in_sizes[5] / (8 * 64);
  int G = out_size / 3;

  // adaptive edge capacity: fixed ~6 MB + 1380 B per edge
  size_t fixed = (size_t)N * 64 * 4 * 2 + (size_t)N * 4 * 7 + (1 << 20);
  int ecap = (int)((ws_size > fixed ? ws_size - fixed : 0) / 1380);
  if (ecap > ECAP_MAX) ecap = ECAP_MAX;

  char* w = (char*)d_ws;
  auto alloc = [&](size_t bytes) {
    void* p = (void*)w;
    w += (bytes + 255) & ~(size_t)255;
    return p;
  };
  float* h0 = (float*)alloc((size_t)N * 64 * 4);
  float* h1 = (float*)alloc((size_t)N * 64 * 4);
  float* Yc = (float*)alloc((size_t)ecap * 16 * 4);
  float* fc = (float*)alloc((size_t)ecap * 8 * 4);
  float* act3 = (float*)alloc((size_t)ecap * 64 * 4);
  float* Rbuf = (float*)alloc((size_t)ecap * 256 * 4);
  int* send = (int*)alloc((size_t)ecap * 4);
  int* off = (int*)alloc((size_t)(N + 1) * 4);
  int* deg = (int*)alloc((size_t)N * 4);
  int* cur = (int*)alloc((size_t)N * 4);
  int* spec = (int*)alloc((size_t)N * 4);
  float* node_e0 = (float*)alloc((size_t)N * 4);
  float* eread = (float*)alloc((size_t)N * 4 * 4);

  hipMemsetAsync(deg, 0, (size_t)N * 4, stream);
  hipMemsetAsync(cur, 0, (size_t)N * 4, stream);
  hipMemsetAsync(eread, 0, (size_t)N * 4 * 4, stream);

  node_init_k<<<(N + 3) / 4, 256, 0, stream>>>(attrs, ae, Wemb, h0, spec,
                                               node_e0, N, NE);
  edge_count_k<<<(E + 255) / 256, 256, 0, stream>>>(pos, shifts, ei, deg, E);
  scan_deg_k<<<1, 1024, 0, stream>>>(deg, off, N);
  edge_fill_k<<<(E + 255) / 256, 256, 0, stream>>>(pos, shifts, ei, off, cur,
                                                   send, Yc, fc, E, ecap);
  const int* nact_p = off + N;
  float* hin = h0;
  float* hout = h1;
  for (int l = 0; l < nlayer; ++l) {
    mlp123_k<<<(E + ATILE - 1) / ATILE, 512, 0, stream>>>(fc, Wr1, Wr2, Wr3,
                                                          nact_p, act3, l, ecap);
    mlp4_k<<<(E + MT - 1) / MT, 512, 0, stream>>>(act3, Wr4, nact_p, Rbuf, l,
                                                  ecap);
    gather_node_k<<<(N + 7) / 8, 512, 0, stream>>>(hin, hout, Rbuf, Wsc, Wp,
                                                   Wrd, Yc, send, off, spec,
                                                   eread, N, NE, l);
    float* t = hin;
    hin = hout;
    hout = t;
  }
  reduce_energy_k<<<G, 256, 0, stream>>>(node_e0, eread, batch, (float*)d_out,
                                         N, G);
}

// Round 9
// 215.806 us; speedup vs baseline: 21.1096x; 1.0418x over previous
//
#include <hip/hip_runtime.h>
#include <math.h>
#include <stdint.h>

// EMACE forward, f32.
// R9 changes vs R8:
//  - mlp_all_k: L1+L2+L3+L4 fused per layer on 256-edge LDS tiles.
//    act3 intermediate eliminated (23 MB/layer traffic + 2 dispatches).
//    W4 streamed through the W2/W3 LDS space in two 128-col halves.
//  - no in-graph memsets: clear_k zeroes deg/cur; eread store/add flag.
//  - reduce_energy_k: binary-search segment bounds on sorted batch.

#define PI_F 3.14159265358979323846f
#define ECAP_MAX 72000  // active-edge capacity (expected ~45k)

__device__ __forceinline__ float silu_f(float x) { return x / (1.f + __expf(-x)); }

#define LDSFENCE() asm volatile("s_waitcnt lgkmcnt(0)" ::: "memory")

// ---------------------------------------------------------------- clear
__global__ void clear_k(int* __restrict__ deg, int* __restrict__ cur, int N) {
  int i = blockIdx.x * blockDim.x + threadIdx.x;
  if (i < N) {
    deg[i] = 0;
    cur[i] = 0;
  }
}

// ---------------------------------------------------------------- node init
__global__ void node_init_k(const float* __restrict__ attrs,
                            const float* __restrict__ ae,
                            const float* __restrict__ Wemb,
                            float* __restrict__ h0, int* __restrict__ spec,
                            float* __restrict__ node_e0, int N, int NE) {
  int n = (int)((blockIdx.x * blockDim.x + threadIdx.x) >> 6);
  int lane = threadIdx.x & 63;
  if (n >= N) return;
  const float* a = attrs + (size_t)n * NE;
  int sp = 0;
  for (int e = 0; e < NE; ++e)
    if (a[e] > 0.5f) sp = e;
  h0[(size_t)n * 64 + lane] = Wemb[sp * 64 + lane];
  if (lane == 0) {
    spec[n] = sp;
    node_e0[n] = ae[sp];
  }
}

// ---------------------------------------------------------------- edge pass 1
__global__ void edge_count_k(const float* __restrict__ pos,
                             const float* __restrict__ shifts,
                             const int* __restrict__ ei,
                             int* __restrict__ deg, int E) {
  int e = blockIdx.x * blockDim.x + threadIdx.x;
  if (e >= E) return;
  int s = ei[e], r = ei[E + e];
  float dx = pos[r * 3 + 0] - pos[s * 3 + 0] + shifts[e * 3 + 0];
  float dy = pos[r * 3 + 1] - pos[s * 3 + 1] + shifts[e * 3 + 1];
  float dz = pos[r * 3 + 2] - pos[s * 3 + 2] + shifts[e * 3 + 2];
  float d2 = dx * dx + dy * dy + dz * dz;
  if (d2 < 25.0f) atomicAdd(&deg[r], 1);
}

// ---------------------------------------------------------------- scan
__global__ void scan_deg_k(const int* __restrict__ deg, int* __restrict__ off,
                           int N) {
  __shared__ int sdat[1024];
  int tid = threadIdx.x;
  int chunk = (N + 1023) / 1024;
  int s0 = tid * chunk, s1 = min(s0 + chunk, N);
  int s = 0;
  for (int i = s0; i < s1; ++i) s += deg[i];
  sdat[tid] = s;
  __syncthreads();
  for (int d = 1; d < 1024; d <<= 1) {
    int v = (tid >= d) ? sdat[tid - d] : 0;
    __syncthreads();
    sdat[tid] += v;
    __syncthreads();
  }
  int run = sdat[tid] - s;  // exclusive prefix
  for (int i = s0; i < s1; ++i) {
    off[i] = run;
    run += deg[i];
  }
  if (tid == 1023) off[N] = sdat[1023];
}

// ---------------------------------------------------------------- edge pass 2
__global__ void edge_fill_k(const float* __restrict__ pos,
                            const float* __restrict__ shifts,
                            const int* __restrict__ ei,
                            const int* __restrict__ off, int* __restrict__ cur,
                            int* __restrict__ send, float* __restrict__ Yc,
                            float* __restrict__ fc, int E, int ecap) {
  int e = blockIdx.x * blockDim.x + threadIdx.x;
  if (e >= E) return;
  int s = ei[e], r = ei[E + e];
  float dx = pos[r * 3 + 0] - pos[s * 3 + 0] + shifts[e * 3 + 0];
  float dy = pos[r * 3 + 1] - pos[s * 3 + 1] + shifts[e * 3 + 1];
  float dz = pos[r * 3 + 2] - pos[s * 3 + 2] + shifts[e * 3 + 2];
  float rr = sqrtf(dx * dx + dy * dy + dz * dz + 1e-12f);
  if (rr >= 5.0f) return;  // inactive edge: cutoff=0 -> R=0 -> msg=0
  int p = off[r] + atomicAdd(&cur[r], 1);
  if (p >= ecap) return;  // statistically impossible; memory-safety guard
  send[p] = s;
  float ir = 1.f / rr;
  float x = dx * ir, y = dy * ir, z = dz * ir;
  const float s3 = 1.73205080757f, s5 = 2.23606797750f, s15 = 3.87298334621f;
  const float c70 = 2.09165006634f;   // sqrt(70)/4
  const float c105 = 10.2469507660f;  // sqrt(105)
  const float c42 = 1.62018517460f;   // sqrt(42)/4
  const float c7 = 1.32287565553f;    // sqrt(7)/2
  float* Yp = Yc + (size_t)p * 16;
  float xx = x * x, yy = y * y, zz = z * z;
  Yp[0] = 1.f;
  Yp[1] = s3 * x;
  Yp[2] = s3 * y;
  Yp[3] = s3 * z;
  Yp[4] = s15 * x * y;
  Yp[5] = s15 * y * z;
  Yp[6] = 0.5f * s5 * (3.f * zz - 1.f);
  Yp[7] = s15 * x * z;
  Yp[8] = 0.5f * s15 * (xx - yy);
  Yp[9] = c70 * y * (3.f * xx - yy);
  Yp[10] = c105 * x * y * z;
  Yp[11] = c42 * y * (5.f * zz - 1.f);
  Yp[12] = c7 * z * (5.f * zz - 3.f);
  Yp[13] = c42 * x * (5.f * zz - 1.f);
  Yp[14] = 0.5f * c105 * z * (xx - yy);
  Yp[15] = c70 * x * (xx - 3.f * yy);
  float xr = rr * 0.2f;
  float xr2 = xr * xr, xr4 = xr2 * xr2;
  float xr5 = xr4 * xr, xr6 = xr5 * xr, xr7 = xr6 * xr;
  float poly = 1.f - 21.f * xr5 + 35.f * xr6 - 15.f * xr7;
  float pref = 0.632455532034f /* sqrt(2/5) */ * ir * poly;
  float* fp = fc + (size_t)p * 8;
  // sin(n*pi*xr) via recurrence: s_{n+1} = 2*cos(pi*xr)*s_n - s_{n-1}
  float s1 = sinf(PI_F * xr), c1 = cosf(PI_F * xr);
  float sm = 0.f, sp2 = s1;
  fp[0] = pref * s1;
#pragma unroll
  for (int nb = 2; nb <= 8; ++nb) {
    float sn = 2.f * c1 * sp2 - sm;
    fp[nb - 1] = pref * sn;
    sm = sp2;
    sp2 = sn;
  }
}

// ---------------------------------------------------------------- fused MLP
#define ATILE 256  // edges per block tile

__device__ __forceinline__ void gemm64(const float* __restrict__ sW,
                                       const float* __restrict__ sX,
                                       int ebase, int cbase, float a[8][4]) {
#pragma unroll
  for (int j = 0; j < 8; ++j)
#pragma unroll
    for (int i = 0; i < 4; ++i) a[j][i] = 0.f;
#pragma unroll 4
  for (int k = 0; k < 64; ++k) {
    float4 x0 = *(const float4*)&sX[k * ATILE + ebase];
    float4 x1 = *(const float4*)&sX[k * ATILE + ebase + 4];
    float4 w = *(const float4*)&sW[k * 64 + cbase];
    float xs[8] = {x0.x, x0.y, x0.z, x0.w, x1.x, x1.y, x1.z, x1.w};
    float ws[4] = {w.x, w.y, w.z, w.w};
#pragma unroll
    for (int j = 0; j < 8; ++j)
#pragma unroll
      for (int i = 0; i < 4; ++i) a[j][i] += xs[j] * ws[i];
  }
}

// L1+L2+L3+L4 on one 256-edge tile. LDS: sX 64K + sW1 2K + sWW 32K = 98K.
// sWW holds W2 [0:4096] and W3 [4096:8192] for L2/L3, then is reused as
// the W4 half-buffer [k][128] for the two L4 column halves.
__global__ __launch_bounds__(512, 1) void mlp_all_k(
    const float* __restrict__ fc, const float* __restrict__ Wr1,
    const float* __restrict__ Wr2, const float* __restrict__ Wr3,
    const float* __restrict__ Wr4, const int* __restrict__ nact_p,
    float* __restrict__ Rbuf, int layer, int ecap) {
  __shared__ __attribute__((aligned(16))) float sX[64 * ATILE];  // 64 KB [k][e]
  __shared__ __attribute__((aligned(16))) float sW1[8 * 64];
  __shared__ __attribute__((aligned(16))) float sWW[8192];       // 32 KB
  int nact = min(*nact_p, ecap);
  int t0 = blockIdx.x * ATILE;
  if (t0 >= nact || nact == 0) return;
  int tid = threadIdx.x;
  {
    const float* w1 = Wr1 + (size_t)layer * 512;
    const float* w2 = Wr2 + (size_t)layer * 4096;
    const float* w3 = Wr3 + (size_t)layer * 4096;
    if (tid < 512) sW1[tid] = w1[tid];
    for (int i = tid; i < 4096; i += 512) {
      sWW[i] = w2[i];
      sWW[4096 + i] = w3[i];
    }
    for (int i = tid; i < ATILE * 8; i += 512) {
      int el = i >> 3, k = i & 7;
      int e = min(t0 + el, nact - 1);
      sX[k * ATILE + el] = fc[(size_t)e * 8 + k];
    }
  }
  __syncthreads();

  int wid = tid >> 6, lane = tid & 63;
  int es = (wid >> 1) * 64;
  int ch = (wid & 1) * 32;
  int g = lane >> 3, q = lane & 7;
  int ebase = es + g * 8;
  int cbase = ch + q * 4;

  float y[8][4];
  // ---- L1: k = 0..7
  {
    float a[8][4];
#pragma unroll
    for (int j = 0; j < 8; ++j)
#pragma unroll
      for (int i = 0; i < 4; ++i) a[j][i] = 0.f;
#pragma unroll
    for (int k = 0; k < 8; ++k) {
      float4 x0 = *(const float4*)&sX[k * ATILE + ebase];
      float4 x1 = *(const float4*)&sX[k * ATILE + ebase + 4];
      float4 w = *(const float4*)&sW1[k * 64 + cbase];
      float xs[8] = {x0.x, x0.y, x0.z, x0.w, x1.x, x1.y, x1.z, x1.w};
      float ws[4] = {w.x, w.y, w.z, w.w};
#pragma unroll
      for (int j = 0; j < 8; ++j)
#pragma unroll
        for (int i = 0; i < 4; ++i) a[j][i] += xs[j] * ws[i];
    }
#pragma unroll
    for (int j = 0; j < 8; ++j)
#pragma unroll
      for (int i = 0; i < 4; ++i) y[j][i] = silu_f(a[j][i]);
  }
  __syncthreads();
#pragma unroll
  for (int i = 0; i < 4; ++i) {
    float4 v0 = {y[0][i], y[1][i], y[2][i], y[3][i]};
    float4 v1 = {y[4][i], y[5][i], y[6][i], y[7][i]};
    *(float4*)&sX[(cbase + i) * ATILE + ebase] = v0;
    *(float4*)&sX[(cbase + i) * ATILE + ebase + 4] = v1;
  }
  __syncthreads();
  // ---- L2 (W2 = sWW[0:4096])
  {
    float a[8][4];
    gemm64(sWW, sX, ebase, cbase, a);
#pragma unroll
    for (int j = 0; j < 8; ++j)
#pragma unroll
      for (int i = 0; i < 4; ++i) y[j][i] = silu_f(a[j][i]);
  }
  __syncthreads();
#pragma unroll
  for (int i = 0; i < 4; ++i) {
    float4 v0 = {y[0][i], y[1][i], y[2][i], y[3][i]};
    float4 v1 = {y[4][i], y[5][i], y[6][i], y[7][i]};
    *(float4*)&sX[(cbase + i) * ATILE + ebase] = v0;
    *(float4*)&sX[(cbase + i) * ATILE + ebase + 4] = v1;
  }
  __syncthreads();
  // ---- L3 (W3 = sWW[4096:8192]) -> act back to sX
  {
    float a[8][4];
    gemm64(sWW + 4096, sX, ebase, cbase, a);
#pragma unroll
    for (int j = 0; j < 8; ++j)
#pragma unroll
      for (int i = 0; i < 4; ++i) y[j][i] = silu_f(a[j][i]);
  }
  __syncthreads();
#pragma unroll
  for (int i = 0; i < 4; ++i) {
    float4 v0 = {y[0][i], y[1][i], y[2][i], y[3][i]};
    float4 v1 = {y[4][i], y[5][i], y[6][i], y[7][i]};
    *(float4*)&sX[(cbase + i) * ATILE + ebase] = v0;
    *(float4*)&sX[(cbase + i) * ATILE + ebase + 4] = v1;
  }
  // ---- L4: 64 -> 256 over two 128-col halves; sWW reused as [k][128]
  const float* w4 = Wr4 + (size_t)layer * 16384;
  int egrp = tid >> 4;  // 0..31 -> 8 edges each (covers 256)
  int cgrp = tid & 15;  // 0..15 -> 8 cols each (covers 128 per half)
  int eb = egrp * 8, cb = cgrp * 8;
#pragma unroll
  for (int half = 0; half < 2; ++half) {
    __syncthreads();  // act writes done (h0) / prev half compute done (h1)
    for (int i = tid; i < 8192; i += 512) {
      int k = i >> 7, cc = i & 127;
      sWW[k * 128 + cc] = w4[k * 256 + half * 128 + cc];
    }
    __syncthreads();
    float a[8][8];
#pragma unroll
    for (int j = 0; j < 8; ++j)
#pragma unroll
      for (int i = 0; i < 8; ++i) a[j][i] = 0.f;
#pragma unroll 2
    for (int k = 0; k < 64; ++k) {
      float4 x0 = *(const float4*)&sX[k * ATILE + eb];
      float4 x1 = *(const float4*)&sX[k * ATILE + eb + 4];
      float4 w0 = *(const float4*)&sWW[k * 128 + cb];
      float4 w1 = *(const float4*)&sWW[k * 128 + cb + 4];
      float xs[8] = {x0.x, x0.y, x0.z, x0.w, x1.x, x1.y, x1.z, x1.w};
      float ws[8] = {w0.x, w0.y, w0.z, w0.w, w1.x, w1.y, w1.z, w1.w};
#pragma unroll
      for (int j = 0; j < 8; ++j)
#pragma unroll
        for (int i = 0; i < 8; ++i) a[j][i] += xs[j] * ws[i];
    }
#pragma unroll
    for (int j = 0; j < 8; ++j) {
      int eg = t0 + eb + j;
      if (eg < nact) {
        float4 v0 = {a[j][0], a[j][1], a[j][2], a[j][3]};
        float4 v1 = {a[j][4], a[j][5], a[j][6], a[j][7]};
        *(float4*)&Rbuf[(size_t)eg * 256 + half * 128 + cb] = v0;
        *(float4*)&Rbuf[(size_t)eg * 256 + half * 128 + cb + 4] = v1;
      }
    }
  }
}

// ---------------------------------------------------------------- node layer
// Streams per-edge (R, hs, Y) with 4-edge load-phase ILP, accumulates
// acc[16], then node update (Wp from LDS) + per-node readout (NO atomics).
__global__ __launch_bounds__(512, 2) void gather_node_k(
    const float* __restrict__ h_in, float* __restrict__ h_out,
    const float* __restrict__ Rbuf, const float* __restrict__ Wsc,
    const float* __restrict__ Wp, const float* __restrict__ Wread,
    const float* __restrict__ Yc, const int* __restrict__ send,
    const int* __restrict__ off, const int* __restrict__ spec,
    float* __restrict__ eread, int N, int NE, int layer) {
  __shared__ __attribute__((aligned(16))) float sWp[4096];  // 16 KB
  __shared__ __attribute__((aligned(16))) float sVec[8][64];
  int tid = threadIdx.x;
  {
    const float* wp = Wp + (size_t)layer * 4096;
    for (int i = tid; i < 4096; i += 512) sWp[i] = wp[i];
  }
  __syncthreads();
  int wid = tid >> 6, lane = tid & 63;
  int n = blockIdx.x * 8 + wid;
  if (n >= N) return;

  int base = off[n];
  int deg = off[n + 1] - base;
  float acc[16];
#pragma unroll
  for (int i = 0; i < 16; ++i) acc[i] = 0.f;

  for (int b = 0; b < deg; b += 4) {
    int m = min(4, deg - b);
    int eu[4];
    float hs[4], r[4][4];
    // ---- load phase: independent vector loads in flight
#pragma unroll
    for (int j = 0; j < 4; ++j) {
      int e = base + b + (j < m ? j : m - 1);
      eu[j] = __builtin_amdgcn_readfirstlane(e);
      hs[j] = h_in[(size_t)send[eu[j]] * 64 + lane];
#pragma unroll
      for (int l = 0; l < 4; ++l)
        r[j][l] = Rbuf[(size_t)eu[j] * 256 + l * 64 + lane];
    }
    // ---- compute phase
#pragma unroll
    for (int j = 0; j < 4; ++j) {
      if (j < m) {  // wave-uniform
        const float* yp = Yc + (size_t)eu[j] * 16;  // uniform -> s_loads
        float t0_ = hs[j] * r[j][0], t1_ = hs[j] * r[j][1];
        float t2_ = hs[j] * r[j][2], t3_ = hs[j] * r[j][3];
        acc[0] += yp[0] * t0_;
        acc[1] += yp[1] * t1_;   acc[2] += yp[2] * t1_;   acc[3] += yp[3] * t1_;
        acc[4] += yp[4] * t2_;   acc[5] += yp[5] * t2_;   acc[6] += yp[6] * t2_;
        acc[7] += yp[7] * t2_;   acc[8] += yp[8] * t2_;
        acc[9] += yp[9] * t3_;   acc[10] += yp[10] * t3_;
        acc[11] += yp[11] * t3_; acc[12] += yp[12] * t3_;
        acc[13] += yp[13] * t3_; acc[14] += yp[14] * t3_;
        acc[15] += yp[15] * t3_;
      }
    }
  }

  // node update: inv = A0 + sum_lm A^2   (A = acc / 16)
  float inv = acc[0] * 0.0625f;
#pragma unroll
  for (int i = 0; i < 16; ++i) {
    float a2 = acc[i] * 0.0625f;
    inv += a2 * a2;
  }
  float* sv = sVec[wid];
  sv[lane] = inv;
  LDSFENCE();
  int sp = spec[n];
  const float* wsc = Wsc + ((size_t)layer * NE + sp) * 4096;
  const float* hold = h_in + (size_t)n * 64;
  float hv = 0.f;
#pragma unroll 4
  for (int k = 0; k < 64; ++k) {
    hv += sv[k] * sWp[k * 64 + lane];
    hv += hold[k] * wsc[k * 64 + lane];
  }
  h_out[(size_t)n * 64 + lane] = hv;
  LDSFENCE();
  sv[lane] = hv;
  LDSFENCE();
  if (lane < 3) {
    const float* wr = Wread + (size_t)layer * 64 * 3;
    float s = 0.f;
#pragma unroll 8
    for (int d = 0; d < 64; ++d) s += sv[d] * wr[d * 3 + lane];
    if (layer == 0)
      eread[(size_t)n * 4 + lane] = s;   // first layer: store (no memset)
    else
      eread[(size_t)n * 4 + lane] += s;  // private to this wave: no atomic
  }
}

// ---------------------------------------------------------------- energy out
// One block per graph; batch is sorted -> binary-search the segment.
__global__ __launch_bounds__(256) void reduce_energy_k(
    const float* __restrict__ node_e0, const float* __restrict__ eread,
    const int* __restrict__ batch, float* __restrict__ out, int N, int G) {
  __shared__ float red[256 * 4];
  int g = blockIdx.x;
  int tid = threadIdx.x;
  int lo = 0, hi = N;
  while (lo < hi) {
    int mid = (lo + hi) >> 1;
    if (batch[mid] < g) lo = mid + 1; else hi = mid;
  }
  int start = lo;
  hi = N;
  while (lo < hi) {
    int mid = (lo + hi) >> 1;
    if (batch[mid] < g + 1) lo = mid + 1; else hi = mid;
  }
  int end = lo;
  float p0 = 0.f, p1 = 0.f, p2 = 0.f;
  for (int n = start + tid; n < end; n += 256) {
    float e0 = node_e0[n];
    p0 += e0 + eread[(size_t)n * 4 + 0];
    p1 += e0 + eread[(size_t)n * 4 + 1];
    p2 += e0 + eread[(size_t)n * 4 + 2];
  }
  red[tid * 4 + 0] = p0;
  red[tid * 4 + 1] = p1;
  red[tid * 4 + 2] = p2;
  __syncthreads();
  for (int s = 128; s > 0; s >>= 1) {
    if (tid < s) {
      red[tid * 4 + 0] += red[(tid + s) * 4 + 0];
      red[tid * 4 + 1] += red[(tid + s) * 4 + 1];
      red[tid * 4 + 2] += red[(tid + s) * 4 + 2];
    }
    __syncthreads();
  }
  if (tid < 3) out[g * 3 + tid] = red[tid];
}

// ---------------------------------------------------------------- host
extern "C" void kernel_launch(void* const* d_in, const int* in_sizes, int n_in,
                              void* d_out, int out_size, void* d_ws,
                              size_t ws_size, hipStream_t stream) {
  const float* pos = (const float*)d_in[0];
  const float* shifts = (const float*)d_in[1];
  const float* attrs = (const float*)d_in[2];
  const float* ae = (const float*)d_in[3];
  const float* Wemb = (const float*)d_in[4];
  const float* Wr1 = (const float*)d_in[5];
  const float* Wr2 = (const float*)d_in[6];
  const float* Wr3 = (const float*)d_in[7];
  const float* Wr4 = (const float*)d_in[8];
  const float* Wsc = (const float*)d_in[9];
  const float* Wp = (const float*)d_in[10];
  const float* Wrd = (const float*)d_in[11];
  const int* ei = (const int*)d_in[12];
  const int* batch = (const int*)d_in[13];

  int N = in_sizes[0] / 3;
  int E = in_sizes[12] / 2;
  int NE = in_sizes[3];
  int nlayer = in_sizes[5] / (8 * 64);
  int G = out_size / 3;

  // adaptive edge capacity: fixed ~6 MB + 1124 B per edge
  size_t fixed = (size_t)N * 64 * 4 * 2 + (size_t)N * 4 * 7 + (1 << 20);
  int ecap = (int)((ws_size > fixed ? ws_size - fixed : 0) / 1124);
  if (ecap > ECAP_MAX) ecap = ECAP_MAX;

  char* w = (char*)d_ws;
  auto alloc = [&](size_t bytes) {
    void* p = (void*)w;
    w += (bytes + 255) & ~(size_t)255;
    return p;
  };
  float* h0 = (float*)alloc((size_t)N * 64 * 4);
  float* h1 = (float*)alloc((size_t)N * 64 * 4);
  float* Yc = (float*)alloc((size_t)ecap * 16 * 4);
  float* fc = (float*)alloc((size_t)ecap * 8 * 4);
  float* Rbuf = (float*)alloc((size_t)ecap * 256 * 4);
  int* send = (int*)alloc((size_t)ecap * 4);
  int* off = (int*)alloc((size_t)(N + 1) * 4);
  int* deg = (int*)alloc((size_t)N * 4);
  int* cur = (int*)alloc((size_t)N * 4);
  int* spec = (int*)alloc((size_t)N * 4);
  float* node_e0 = (float*)alloc((size_t)N * 4);
  float* eread = (float*)alloc((size_t)N * 4 * 4);

  clear_k<<<(N + 255) / 256, 256, 0, stream>>>(deg, cur, N);
  node_init_k<<<(N + 3) / 4, 256, 0, stream>>>(attrs, ae, Wemb, h0, spec,
                                               node_e0, N, NE);
  edge_count_k<<<(E + 255) / 256, 256, 0, stream>>>(pos, shifts, ei, deg, E);
  scan_deg_k<<<1, 1024, 0, stream>>>(deg, off, N);
  edge_fill_k<<<(E + 255) / 256, 256, 0, stream>>>(pos, shifts, ei, off, cur,
                                                   send, Yc, fc, E, ecap);
  const int* nact_p = off + N;
  float* hin = h0;
  float* hout = h1;
  for (int l = 0; l < nlayer; ++l) {
    mlp_all_k<<<(E + ATILE - 1) / ATILE, 512, 0, stream>>>(
        fc, Wr1, Wr2, Wr3, Wr4, nact_p, Rbuf, l, ecap);
    gather_node_k<<<(N + 7) / 8, 512, 0, stream>>>(hin, hout, Rbuf, Wsc, Wp,
                                                   Wrd, Yc, send, off, spec,
                                                   eread, N, NE, l);
    float* t = hin;
    hin = hout;
    hout = t;
  }
  reduce_energy_k<<<G, 256, 0, stream>>>(node_e0, eread, batch, (float*)d_out,
                                         N, G);
}

// Round 10
// 203.591 us; speedup vs baseline: 22.3761x; 1.0600x over previous
//
#include <hip/hip_runtime.h>
#include <math.h>
#include <stdint.h>

// EMACE forward, f32.
// R10 changes vs R9 (mlp_all_k only):
//  - ATILE 256->128, padded stride SXT=132: LDS 98->67.8 KB -> 2 blocks/CU,
//    grid ~352 working blocks (was ~180 at 1/CU with idle CUs).
//  - act-write row stride no longer ==0 mod 32 banks (8-way -> <=4-way).
//  - L4 column quads split (cb, cb+64): w-reads 4-way -> 2-way (free).

#define PI_F 3.14159265358979323846f
#define ECAP_MAX 72000  // active-edge capacity (expected ~45k)

__device__ __forceinline__ float silu_f(float x) { return x / (1.f + __expf(-x)); }

#define LDSFENCE() asm volatile("s_waitcnt lgkmcnt(0)" ::: "memory")

// ---------------------------------------------------------------- clear
__global__ void clear_k(int* __restrict__ deg, int* __restrict__ cur, int N) {
  int i = blockIdx.x * blockDim.x + threadIdx.x;
  if (i < N) {
    deg[i] = 0;
    cur[i] = 0;
  }
}

// ---------------------------------------------------------------- node init
__global__ void node_init_k(const float* __restrict__ attrs,
                            const float* __restrict__ ae,
                            const float* __restrict__ Wemb,
                            float* __restrict__ h0, int* __restrict__ spec,
                            float* __restrict__ node_e0, int N, int NE) {
  int n = (int)((blockIdx.x * blockDim.x + threadIdx.x) >> 6);
  int lane = threadIdx.x & 63;
  if (n >= N) return;
  const float* a = attrs + (size_t)n * NE;
  int sp = 0;
  for (int e = 0; e < NE; ++e)
    if (a[e] > 0.5f) sp = e;
  h0[(size_t)n * 64 + lane] = Wemb[sp * 64 + lane];
  if (lane == 0) {
    spec[n] = sp;
    node_e0[n] = ae[sp];
  }
}

// ---------------------------------------------------------------- edge pass 1
__global__ void edge_count_k(const float* __restrict__ pos,
                             const float* __restrict__ shifts,
                             const int* __restrict__ ei,
                             int* __restrict__ deg, int E) {
  int e = blockIdx.x * blockDim.x + threadIdx.x;
  if (e >= E) return;
  int s = ei[e], r = ei[E + e];
  float dx = pos[r * 3 + 0] - pos[s * 3 + 0] + shifts[e * 3 + 0];
  float dy = pos[r * 3 + 1] - pos[s * 3 + 1] + shifts[e * 3 + 1];
  float dz = pos[r * 3 + 2] - pos[s * 3 + 2] + shifts[e * 3 + 2];
  float d2 = dx * dx + dy * dy + dz * dz;
  if (d2 < 25.0f) atomicAdd(&deg[r], 1);
}

// ---------------------------------------------------------------- scan
__global__ void scan_deg_k(const int* __restrict__ deg, int* __restrict__ off,
                           int N) {
  __shared__ int sdat[1024];
  int tid = threadIdx.x;
  int chunk = (N + 1023) / 1024;
  int s0 = tid * chunk, s1 = min(s0 + chunk, N);
  int s = 0;
  for (int i = s0; i < s1; ++i) s += deg[i];
  sdat[tid] = s;
  __syncthreads();
  for (int d = 1; d < 1024; d <<= 1) {
    int v = (tid >= d) ? sdat[tid - d] : 0;
    __syncthreads();
    sdat[tid] += v;
    __syncthreads();
  }
  int run = sdat[tid] - s;  // exclusive prefix
  for (int i = s0; i < s1; ++i) {
    off[i] = run;
    run += deg[i];
  }
  if (tid == 1023) off[N] = sdat[1023];
}

// ---------------------------------------------------------------- edge pass 2
__global__ void edge_fill_k(const float* __restrict__ pos,
                            const float* __restrict__ shifts,
                            const int* __restrict__ ei,
                            const int* __restrict__ off, int* __restrict__ cur,
                            int* __restrict__ send, float* __restrict__ Yc,
                            float* __restrict__ fc, int E, int ecap) {
  int e = blockIdx.x * blockDim.x + threadIdx.x;
  if (e >= E) return;
  int s = ei[e], r = ei[E + e];
  float dx = pos[r * 3 + 0] - pos[s * 3 + 0] + shifts[e * 3 + 0];
  float dy = pos[r * 3 + 1] - pos[s * 3 + 1] + shifts[e * 3 + 1];
  float dz = pos[r * 3 + 2] - pos[s * 3 + 2] + shifts[e * 3 + 2];
  float rr = sqrtf(dx * dx + dy * dy + dz * dz + 1e-12f);
  if (rr >= 5.0f) return;  // inactive edge: cutoff=0 -> R=0 -> msg=0
  int p = off[r] + atomicAdd(&cur[r], 1);
  if (p >= ecap) return;  // statistically impossible; memory-safety guard
  send[p] = s;
  float ir = 1.f / rr;
  float x = dx * ir, y = dy * ir, z = dz * ir;
  const float s3 = 1.73205080757f, s5 = 2.23606797750f, s15 = 3.87298334621f;
  const float c70 = 2.09165006634f;   // sqrt(70)/4
  const float c105 = 10.2469507660f;  // sqrt(105)
  const float c42 = 1.62018517460f;   // sqrt(42)/4
  const float c7 = 1.32287565553f;    // sqrt(7)/2
  float* Yp = Yc + (size_t)p * 16;
  float xx = x * x, yy = y * y, zz = z * z;
  Yp[0] = 1.f;
  Yp[1] = s3 * x;
  Yp[2] = s3 * y;
  Yp[3] = s3 * z;
  Yp[4] = s15 * x * y;
  Yp[5] = s15 * y * z;
  Yp[6] = 0.5f * s5 * (3.f * zz - 1.f);
  Yp[7] = s15 * x * z;
  Yp[8] = 0.5f * s15 * (xx - yy);
  Yp[9] = c70 * y * (3.f * xx - yy);
  Yp[10] = c105 * x * y * z;
  Yp[11] = c42 * y * (5.f * zz - 1.f);
  Yp[12] = c7 * z * (5.f * zz - 3.f);
  Yp[13] = c42 * x * (5.f * zz - 1.f);
  Yp[14] = 0.5f * c105 * z * (xx - yy);
  Yp[15] = c70 * x * (xx - 3.f * yy);
  float xr = rr * 0.2f;
  float xr2 = xr * xr, xr4 = xr2 * xr2;
  float xr5 = xr4 * xr, xr6 = xr5 * xr, xr7 = xr6 * xr;
  float poly = 1.f - 21.f * xr5 + 35.f * xr6 - 15.f * xr7;
  float pref = 0.632455532034f /* sqrt(2/5) */ * ir * poly;
  float* fp = fc + (size_t)p * 8;
  // sin(n*pi*xr) via recurrence: s_{n+1} = 2*cos(pi*xr)*s_n - s_{n-1}
  float s1 = sinf(PI_F * xr), c1 = cosf(PI_F * xr);
  float sm = 0.f, sp2 = s1;
  fp[0] = pref * s1;
#pragma unroll
  for (int nb = 2; nb <= 8; ++nb) {
    float sn = 2.f * c1 * sp2 - sm;
    fp[nb - 1] = pref * sn;
    sm = sp2;
    sp2 = sn;
  }
}

// ---------------------------------------------------------------- fused MLP
#define ATILE 128  // edges per block tile
#define SXT 132    // padded sX row stride (floats)

// 64->64 GEMM: a[4e][4c] += X[k][e-quad] * W[k][c-quad], K=64
__device__ __forceinline__ void gemm64(const float* __restrict__ sW,
                                       const float* __restrict__ sX,
                                       int ebase, int cbase, float a[4][4]) {
#pragma unroll
  for (int j = 0; j < 4; ++j)
#pragma unroll
    for (int i = 0; i < 4; ++i) a[j][i] = 0.f;
#pragma unroll 4
  for (int k = 0; k < 64; ++k) {
    float4 x = *(const float4*)&sX[k * SXT + ebase];
    float4 w = *(const float4*)&sW[k * 64 + cbase];
    float xs[4] = {x.x, x.y, x.z, x.w};
    float ws[4] = {w.x, w.y, w.z, w.w};
#pragma unroll
    for (int j = 0; j < 4; ++j)
#pragma unroll
      for (int i = 0; i < 4; ++i) a[j][i] += xs[j] * ws[i];
  }
}

// L1+L2+L3+L4 on one 128-edge tile. LDS: sX 33.8K + sW1 2K + sWW 32K = 67.8K
// -> 2 blocks/CU. sWW holds W2|W3 for L2/L3, then the W4 half-buffers.
__global__ __launch_bounds__(512, 2) void mlp_all_k(
    const float* __restrict__ fc, const float* __restrict__ Wr1,
    const float* __restrict__ Wr2, const float* __restrict__ Wr3,
    const float* __restrict__ Wr4, const int* __restrict__ nact_p,
    float* __restrict__ Rbuf, int layer, int ecap) {
  __shared__ __attribute__((aligned(16))) float sX[64 * SXT];  // 33.8 KB [k][e]
  __shared__ __attribute__((aligned(16))) float sW1[8 * 64];
  __shared__ __attribute__((aligned(16))) float sWW[8192];     // 32 KB
  int nact = min(*nact_p, ecap);
  int t0 = blockIdx.x * ATILE;
  if (t0 >= nact || nact == 0) return;
  int tid = threadIdx.x;
  {
    const float* w1 = Wr1 + (size_t)layer * 512;
    const float* w2 = Wr2 + (size_t)layer * 4096;
    const float* w3 = Wr3 + (size_t)layer * 4096;
    if (tid < 512) sW1[tid] = w1[tid];
    for (int i = tid; i < 4096; i += 512) {
      sWW[i] = w2[i];
      sWW[4096 + i] = w3[i];
    }
    for (int i = tid; i < ATILE * 8; i += 512) {
      int el = i >> 3, k = i & 7;
      int e = min(t0 + el, nact - 1);
      sX[k * SXT + el] = fc[(size_t)e * 8 + k];
    }
  }
  __syncthreads();

  int wid = tid >> 6, lane = tid & 63;
  int stripe = wid >> 1;           // 4 stripes of 32 edges
  int ch = (wid & 1) * 32;         // c-half of 64
  int g = lane >> 3, q = lane & 7;
  int ebase = stripe * 32 + g * 4;
  int cbase = ch + q * 4;

  float y[4][4];
  // ---- L1: k = 0..7
  {
    float a[4][4];
#pragma unroll
    for (int j = 0; j < 4; ++j)
#pragma unroll
      for (int i = 0; i < 4; ++i) a[j][i] = 0.f;
#pragma unroll
    for (int k = 0; k < 8; ++k) {
      float4 x = *(const float4*)&sX[k * SXT + ebase];
      float4 w = *(const float4*)&sW1[k * 64 + cbase];
      float xs[4] = {x.x, x.y, x.z, x.w};
      float ws[4] = {w.x, w.y, w.z, w.w};
#pragma unroll
      for (int j = 0; j < 4; ++j)
#pragma unroll
        for (int i = 0; i < 4; ++i) a[j][i] += xs[j] * ws[i];
    }
#pragma unroll
    for (int j = 0; j < 4; ++j)
#pragma unroll
      for (int i = 0; i < 4; ++i) y[j][i] = silu_f(a[j][i]);
  }
  __syncthreads();
#pragma unroll
  for (int i = 0; i < 4; ++i) {
    float4 v = {y[0][i], y[1][i], y[2][i], y[3][i]};
    *(float4*)&sX[(cbase + i) * SXT + ebase] = v;
  }
  __syncthreads();
  // ---- L2 (W2 = sWW[0:4096])
  {
    float a[4][4];
    gemm64(sWW, sX, ebase, cbase, a);
#pragma unroll
    for (int j = 0; j < 4; ++j)
#pragma unroll
      for (int i = 0; i < 4; ++i) y[j][i] = silu_f(a[j][i]);
  }
  __syncthreads();
#pragma unroll
  for (int i = 0; i < 4; ++i) {
    float4 v = {y[0][i], y[1][i], y[2][i], y[3][i]};
    *(float4*)&sX[(cbase + i) * SXT + ebase] = v;
  }
  __syncthreads();
  // ---- L3 (W3 = sWW[4096:8192])
  {
    float a[4][4];
    gemm64(sWW + 4096, sX, ebase, cbase, a);
#pragma unroll
    for (int j = 0; j < 4; ++j)
#pragma unroll
      for (int i = 0; i < 4; ++i) y[j][i] = silu_f(a[j][i]);
  }
  __syncthreads();
#pragma unroll
  for (int i = 0; i < 4; ++i) {
    float4 v = {y[0][i], y[1][i], y[2][i], y[3][i]};
    *(float4*)&sX[(cbase + i) * SXT + ebase] = v;
  }
  // ---- L4: 64 -> 256 over two 128-col halves; sWW reused as [k][128].
  // Thread owns 4 edges (eb) x col-quads {cb, cb+64} within the half:
  // w-read start banks stride 16B across 16 cgrps -> 2-way (free).
  const float* w4 = Wr4 + (size_t)layer * 16384;
  int egrp = tid >> 4;  // 0..31 -> 4 edges each (covers 128)
  int cgrp = tid & 15;  // 0..15 -> quads at cb and cb+64
  int eb = egrp * 4, cb = cgrp * 4;
#pragma unroll
  for (int half = 0; half < 2; ++half) {
    __syncthreads();  // act writes done (h0) / prev half compute done (h1)
    for (int i = tid; i < 8192; i += 512) {
      int k = i >> 7, cc = i & 127;
      sWW[k * 128 + cc] = w4[k * 256 + half * 128 + cc];
    }
    __syncthreads();
    float a[4][8];
#pragma unroll
    for (int j = 0; j < 4; ++j)
#pragma unroll
      for (int i = 0; i < 8; ++i) a[j][i] = 0.f;
#pragma unroll 2
    for (int k = 0; k < 64; ++k) {
      float4 x = *(const float4*)&sX[k * SXT + eb];
      float4 w0 = *(const float4*)&sWW[k * 128 + cb];
      float4 w1 = *(const float4*)&sWW[k * 128 + cb + 64];
      float xs[4] = {x.x, x.y, x.z, x.w};
      float ws[8] = {w0.x, w0.y, w0.z, w0.w, w1.x, w1.y, w1.z, w1.w};
#pragma unroll
      for (int j = 0; j < 4; ++j)
#pragma unroll
        for (int i = 0; i < 8; ++i) a[j][i] += xs[j] * ws[i];
    }
#pragma unroll
    for (int j = 0; j < 4; ++j) {
      int eg = t0 + eb + j;
      if (eg < nact) {
        float4 v0 = {a[j][0], a[j][1], a[j][2], a[j][3]};
        float4 v1 = {a[j][4], a[j][5], a[j][6], a[j][7]};
        *(float4*)&Rbuf[(size_t)eg * 256 + half * 128 + cb] = v0;
        *(float4*)&Rbuf[(size_t)eg * 256 + half * 128 + cb + 64] = v1;
      }
    }
  }
}

// ---------------------------------------------------------------- node layer
// Streams per-edge (R, hs, Y) with 4-edge load-phase ILP, accumulates
// acc[16], then node update (Wp from LDS) + per-node readout (NO atomics).
__global__ __launch_bounds__(512, 2) void gather_node_k(
    const float* __restrict__ h_in, float* __restrict__ h_out,
    const float* __restrict__ Rbuf, const float* __restrict__ Wsc,
    const float* __restrict__ Wp, const float* __restrict__ Wread,
    const float* __restrict__ Yc, const int* __restrict__ send,
    const int* __restrict__ off, const int* __restrict__ spec,
    float* __restrict__ eread, int N, int NE, int layer) {
  __shared__ __attribute__((aligned(16))) float sWp[4096];  // 16 KB
  __shared__ __attribute__((aligned(16))) float sVec[8][64];
  int tid = threadIdx.x;
  {
    const float* wp = Wp + (size_t)layer * 4096;
    for (int i = tid; i < 4096; i += 512) sWp[i] = wp[i];
  }
  __syncthreads();
  int wid = tid >> 6, lane = tid & 63;
  int n = blockIdx.x * 8 + wid;
  if (n >= N) return;

  int base = off[n];
  int deg = off[n + 1] - base;
  float acc[16];
#pragma unroll
  for (int i = 0; i < 16; ++i) acc[i] = 0.f;

  for (int b = 0; b < deg; b += 4) {
    int m = min(4, deg - b);
    int eu[4];
    float hs[4], r[4][4];
    // ---- load phase: independent vector loads in flight
#pragma unroll
    for (int j = 0; j < 4; ++j) {
      int e = base + b + (j < m ? j : m - 1);
      eu[j] = __builtin_amdgcn_readfirstlane(e);
      hs[j] = h_in[(size_t)send[eu[j]] * 64 + lane];
#pragma unroll
      for (int l = 0; l < 4; ++l)
        r[j][l] = Rbuf[(size_t)eu[j] * 256 + l * 64 + lane];
    }
    // ---- compute phase
#pragma unroll
    for (int j = 0; j < 4; ++j) {
      if (j < m) {  // wave-uniform
        const float* yp = Yc + (size_t)eu[j] * 16;  // uniform -> s_loads
        float t0_ = hs[j] * r[j][0], t1_ = hs[j] * r[j][1];
        float t2_ = hs[j] * r[j][2], t3_ = hs[j] * r[j][3];
        acc[0] += yp[0] * t0_;
        acc[1] += yp[1] * t1_;   acc[2] += yp[2] * t1_;   acc[3] += yp[3] * t1_;
        acc[4] += yp[4] * t2_;   acc[5] += yp[5] * t2_;   acc[6] += yp[6] * t2_;
        acc[7] += yp[7] * t2_;   acc[8] += yp[8] * t2_;
        acc[9] += yp[9] * t3_;   acc[10] += yp[10] * t3_;
        acc[11] += yp[11] * t3_; acc[12] += yp[12] * t3_;
        acc[13] += yp[13] * t3_; acc[14] += yp[14] * t3_;
        acc[15] += yp[15] * t3_;
      }
    }
  }

  // node update: inv = A0 + sum_lm A^2   (A = acc / 16)
  float inv = acc[0] * 0.0625f;
#pragma unroll
  for (int i = 0; i < 16; ++i) {
    float a2 = acc[i] * 0.0625f;
    inv += a2 * a2;
  }
  float* sv = sVec[wid];
  sv[lane] = inv;
  LDSFENCE();
  int sp = spec[n];
  const float* wsc = Wsc + ((size_t)layer * NE + sp) * 4096;
  const float* hold = h_in + (size_t)n * 64;
  float hv = 0.f;
#pragma unroll 4
  for (int k = 0; k < 64; ++k) {
    hv += sv[k] * sWp[k * 64 + lane];
    hv += hold[k] * wsc[k * 64 + lane];
  }
  h_out[(size_t)n * 64 + lane] = hv;
  LDSFENCE();
  sv[lane] = hv;
  LDSFENCE();
  if (lane < 3) {
    const float* wr = Wread + (size_t)layer * 64 * 3;
    float s = 0.f;
#pragma unroll 8
    for (int d = 0; d < 64; ++d) s += sv[d] * wr[d * 3 + lane];
    if (layer == 0)
      eread[(size_t)n * 4 + lane] = s;   // first layer: store (no memset)
    else
      eread[(size_t)n * 4 + lane] += s;  // private to this wave: no atomic
  }
}

// ---------------------------------------------------------------- energy out
// One block per graph; batch is sorted -> binary-search the segment.
__global__ __launch_bounds__(256) void reduce_energy_k(
    const float* __restrict__ node_e0, const float* __restrict__ eread,
    const int* __restrict__ batch, float* __restrict__ out, int N, int G) {
  __shared__ float red[256 * 4];
  int g = blockIdx.x;
  int tid = threadIdx.x;
  int lo = 0, hi = N;
  while (lo < hi) {
    int mid = (lo + hi) >> 1;
    if (batch[mid] < g) lo = mid + 1; else hi = mid;
  }
  int start = lo;
  hi = N;
  while (lo < hi) {
    int mid = (lo + hi) >> 1;
    if (batch[mid] < g + 1) lo = mid + 1; else hi = mid;
  }
  int end = lo;
  float p0 = 0.f, p1 = 0.f, p2 = 0.f;
  for (int n = start + tid; n < end; n += 256) {
    float e0 = node_e0[n];
    p0 += e0 + eread[(size_t)n * 4 + 0];
    p1 += e0 + eread[(size_t)n * 4 + 1];
    p2 += e0 + eread[(size_t)n * 4 + 2];
  }
  red[tid * 4 + 0] = p0;
  red[tid * 4 + 1] = p1;
  red[tid * 4 + 2] = p2;
  __syncthreads();
  for (int s = 128; s > 0; s >>= 1) {
    if (tid < s) {
      red[tid * 4 + 0] += red[(tid + s) * 4 + 0];
      red[tid * 4 + 1] += red[(tid + s) * 4 + 1];
      red[tid * 4 + 2] += red[(tid + s) * 4 + 2];
    }
    __syncthreads();
  }
  if (tid < 3) out[g * 3 + tid] = red[tid];
}

// ---------------------------------------------------------------- host
extern "C" void kernel_launch(void* const* d_in, const int* in_sizes, int n_in,
                              void* d_out, int out_size, void* d_ws,
                              size_t ws_size, hipStream_t stream) {
  const float* pos = (const float*)d_in[0];
  const float* shifts = (const float*)d_in[1];
  const float* attrs = (const float*)d_in[2];
  const float* ae = (const float*)d_in[3];
  const float* Wemb = (const float*)d_in[4];
  const float* Wr1 = (const float*)d_in[5];
  const float* Wr2 = (const float*)d_in[6];
  const float* Wr3 = (const float*)d_in[7];
  const float* Wr4 = (const float*)d_in[8];
  const float* Wsc = (const float*)d_in[9];
  const float* Wp = (const float*)d_in[10];
  const float* Wrd = (const float*)d_in[11];
  const int* ei = (const int*)d_in[12];
  const int* batch = (const int*)d_in[13];

  int N = in_sizes[0] / 3;
  int E = in_sizes[12] / 2;
  int NE = in_sizes[3];
  int nlayer = in_sizes[5] / (8 * 64);
  int G = out_size / 3;

  // adaptive edge capacity: fixed ~6 MB + 1124 B per edge
  size_t fixed = (size_t)N * 64 * 4 * 2 + (size_t)N * 4 * 7 + (1 << 20);
  int ecap = (int)((ws_size > fixed ? ws_size - fixed : 0) / 1124);
  if (ecap > ECAP_MAX) ecap = ECAP_MAX;

  char* w = (char*)d_ws;
  auto alloc = [&](size_t bytes) {
    void* p = (void*)w;
    w += (bytes + 255) & ~(size_t)255;
    return p;
  };
  float* h0 = (float*)alloc((size_t)N * 64 * 4);
  float* h1 = (float*)alloc((size_t)N * 64 * 4);
  float* Yc = (float*)alloc((size_t)ecap * 16 * 4);
  float* fc = (float*)alloc((size_t)ecap * 8 * 4);
  float* Rbuf = (float*)alloc((size_t)ecap * 256 * 4);
  int* send = (int*)alloc((size_t)ecap * 4);
  int* off = (int*)alloc((size_t)(N + 1) * 4);
  int* deg = (int*)alloc((size_t)N * 4);
  int* cur = (int*)alloc((size_t)N * 4);
  int* spec = (int*)alloc((size_t)N * 4);
  float* node_e0 = (float*)alloc((size_t)N * 4);
  float* eread = (float*)alloc((size_t)N * 4 * 4);

  clear_k<<<(N + 255) / 256, 256, 0, stream>>>(deg, cur, N);
  node_init_k<<<(N + 3) / 4, 256, 0, stream>>>(attrs, ae, Wemb, h0, spec,
                                               node_e0, N, NE);
  edge_count_k<<<(E + 255) / 256, 256, 0, stream>>>(pos, shifts, ei, deg, E);
  scan_deg_k<<<1, 1024, 0, stream>>>(deg, off, N);
  edge_fill_k<<<(E + 255) / 256, 256, 0, stream>>>(pos, shifts, ei, off, cur,
                                                   send, Yc, fc, E, ecap);
  const int* nact_p = off + N;
  float* hin = h0;
  float* hout = h1;
  for (int l = 0; l < nlayer; ++l) {
    mlp_all_k<<<(E + ATILE - 1) / ATILE, 512, 0, stream>>>(
        fc, Wr1, Wr2, Wr3, Wr4, nact_p, Rbuf, l, ecap);
    gather_node_k<<<(N + 7) / 8, 512, 0, stream>>>(hin, hout, Rbuf, Wsc, Wp,
                                                   Wrd, Yc, send, off, spec,
                                                   eread, N, NE, l);
    float* t = hin;
    hin = hout;
    hout = t;
  }
  reduce_energy_k<<<G, 256, 0, stream>>>(node_e0, eread, batch, (float*)d_out,
                                         N, G);
}